// Round 1
// baseline (770.565 us; speedup 1.0000x reference)
//
#include <hip/hip_runtime.h>
#include <hip/hip_fp16.h>

typedef unsigned short u16;
typedef __attribute__((ext_vector_type(8))) short bf16x8;
typedef __attribute__((ext_vector_type(4))) float f32x4;

#define T_SEQ 2048
#define DIM 1024
#define NB 4

__device__ __forceinline__ u16 f2bf(float f) {
  union { float f; unsigned u; } c; c.f = f;
  unsigned r = c.u + 0x7fffu + ((c.u >> 16) & 1u);
  return (u16)(r >> 16);
}

__device__ __forceinline__ void gload_lds16(const void* g, void* l) {
  __builtin_amdgcn_global_load_lds((const __attribute__((address_space(1))) void*)g,
                                   (__attribute__((address_space(3))) void*)l, 16, 0, 0);
}

// ---------------- LayerNorm: x (f32) -> x_norm (bf16) ----------------
__global__ __launch_bounds__(256) void ln_kernel(const float* __restrict__ x,
                                                 const float* __restrict__ gamma,
                                                 const float* __restrict__ beta,
                                                 u16* __restrict__ xn) {
  const int row = blockIdx.x;
  const int tid = threadIdx.x;
  const float4 v = *(const float4*)(x + (size_t)row * DIM + tid * 4);
  float s  = v.x + v.y + v.z + v.w;
  float ss = v.x * v.x + v.y * v.y + v.z * v.z + v.w * v.w;
#pragma unroll
  for (int o = 32; o > 0; o >>= 1) { s += __shfl_down(s, o); ss += __shfl_down(ss, o); }
  __shared__ float rs[4], rss[4];
  const int wid = tid >> 6, lane = tid & 63;
  if (lane == 0) { rs[wid] = s; rss[wid] = ss; }
  __syncthreads();
  s  = rs[0] + rs[1] + rs[2] + rs[3];
  ss = rss[0] + rss[1] + rss[2] + rss[3];
  const float mu = s * (1.f / DIM);
  const float var = ss * (1.f / DIM) - mu * mu;
  const float rstd = rsqrtf(var + 1e-5f);
  const float4 g  = *(const float4*)(gamma + tid * 4);
  const float4 be = *(const float4*)(beta + tid * 4);
  ushort4 o;
  o.x = f2bf((v.x - mu) * rstd * g.x + be.x);
  o.y = f2bf((v.y - mu) * rstd * g.y + be.y);
  o.z = f2bf((v.z - mu) * rstd * g.z + be.z);
  o.w = f2bf((v.w - mu) * rstd * g.w + be.w);
  *(ushort4*)(xn + (size_t)row * DIM + tid * 4) = o;
}

// ---------------- f32 -> bf16 weight convert ----------------
__global__ __launch_bounds__(256) void wcvt(const float* __restrict__ w, u16* __restrict__ o) {
  const size_t t = (size_t)blockIdx.x * 256 + threadIdx.x;
  const float4 v = *(const float4*)(w + t * 4);
  ushort4 u; u.x = f2bf(v.x); u.y = f2bf(v.y); u.z = f2bf(v.z); u.w = f2bf(v.w);
  *(ushort4*)(o + t * 4) = u;
}

// ---------------- GEMM: C[M,N] = A[M,K] * B[N,K]^T  (bf16 in, fp32 acc) ----
// EPI 0: store bf16          EPI 1: store fp16, *scale
// EPI 2: store bf16, + aux residual (f32, batched)   EPI 3: store f32, +bias[col], relu
template <int EPI>
__global__ __launch_bounds__(256) void gemm_bt(
    const u16* __restrict__ A, const u16* __restrict__ B, void* __restrict__ Cv,
    int K, int lda, int ldb, int ldc,
    long sA, long sB, long sC,
    const float* __restrict__ aux, long sAux, float scale) {
  __shared__ __align__(16) u16 As[128 * 64];
  __shared__ __align__(16) u16 Bs[128 * 64];
  const int bz = blockIdx.z;
  const u16* Ab = A + (size_t)bz * sA;
  const u16* Bb = B + (size_t)bz * sB;
  const int tileM = blockIdx.y * 128;
  const int tileN = blockIdx.x * 128;
  const int tid = threadIdx.x;
  const int lane = tid & 63;
  const int wid = tid >> 6;
  const int wm = wid >> 1, wn = wid & 1;

  f32x4 acc[4][4] = {};

  for (int k0 = 0; k0 < K; k0 += 64) {
#pragma unroll
    for (int r = 0; r < 4; ++r) {
      const int e = r * 2048 + tid * 8;
      const int row = e >> 6, kk = e & 63;
      gload_lds16(Ab + (size_t)(tileM + row) * lda + (k0 + kk), &As[e]);
      gload_lds16(Bb + (size_t)(tileN + row) * ldb + (k0 + kk), &Bs[e]);
    }
    __syncthreads();
#pragma unroll
    for (int kk = 0; kk < 64; kk += 32) {
      bf16x8 af[4], bh[4];
      const int koff = kk + ((lane >> 4) << 3);
#pragma unroll
      for (int i = 0; i < 4; ++i) {
        af[i] = *(const bf16x8*)&As[(wm * 64 + i * 16 + (lane & 15)) * 64 + koff];
        bh[i] = *(const bf16x8*)&Bs[(wn * 64 + i * 16 + (lane & 15)) * 64 + koff];
      }
#pragma unroll
      for (int i = 0; i < 4; ++i)
#pragma unroll
        for (int j = 0; j < 4; ++j)
          acc[i][j] = __builtin_amdgcn_mfma_f32_16x16x32_bf16(af[i], bh[j], acc[i][j], 0, 0, 0);
    }
    __syncthreads();
  }

  const int r0 = tileM + wm * 64 + ((lane >> 4) << 2);
  const int c0 = tileN + wn * 64 + (lane & 15);
#pragma unroll
  for (int i = 0; i < 4; ++i)
#pragma unroll
    for (int j = 0; j < 4; ++j)
#pragma unroll
      for (int r = 0; r < 4; ++r) {
        const int row = r0 + i * 16 + r, col = c0 + j * 16;
        const size_t idx = (size_t)row * ldc + col;
        float v = acc[i][j][r];
        if constexpr (EPI == 0) {
          ((u16*)Cv + (size_t)bz * sC)[idx] = f2bf(v);
        } else if constexpr (EPI == 1) {
          ((__half*)Cv + (size_t)bz * sC)[idx] = __float2half(v * scale);
        } else if constexpr (EPI == 2) {
          v += (aux + (size_t)bz * sAux)[idx];
          ((u16*)Cv + (size_t)bz * sC)[idx] = f2bf(v);
        } else {
          v += aux[col];
          ((float*)Cv + (size_t)bz * sC)[idx] = fmaxf(v, 0.f);
        }
      }
}

// ---------------- per-column (axis=i) max & 1/sum over valid rows ----------
__global__ __launch_bounds__(256) void colreduce(const __half* __restrict__ S,
                                                 const int* __restrict__ l,
                                                 float* __restrict__ m, float* __restrict__ rz) {
  const int b = blockIdx.y;
  const int j = blockIdx.x * 256 + threadIdx.x;
  const __half* Sb = S + (size_t)b * T_SEQ * T_SEQ;
  const int L = l[b];
  float mm = -1e30f, z = 0.f;
  for (int i = 0; i < L; ++i) {
    const float s = __half2float(Sb[(size_t)i * T_SEQ + j]);
    if (s > mm) { z *= __expf(mm - s); mm = s; z += 1.f; }
    else z += __expf(s - mm);
  }
  m[b * T_SEQ + j] = mm;
  rz[b * T_SEQ + j] = 1.f / z;
}

// ---------------- P = exp(S - m) / Z  (bf16, row-masked) -------------------
__global__ __launch_bounds__(256) void pbuild(const __half* __restrict__ S,
                                              const int* __restrict__ l,
                                              const float* __restrict__ m,
                                              const float* __restrict__ rz,
                                              u16* __restrict__ P) {
  const int b = blockIdx.x >> 11;
  const int i = blockIdx.x & (T_SEQ - 1);
  const int j0 = threadIdx.x * 8;
  const size_t off = ((size_t)blockIdx.x << 11) + j0;
  ushort4 o0, o1;
  if (i < l[b]) {
    const __half* sp = S + off;
    const float* mp = m + b * T_SEQ + j0;
    const float* zp = rz + b * T_SEQ + j0;
    u16 tmp[8];
#pragma unroll
    for (int t = 0; t < 8; ++t)
      tmp[t] = f2bf(__expf(__half2float(sp[t]) - mp[t]) * zp[t]);
    o0 = make_ushort4(tmp[0], tmp[1], tmp[2], tmp[3]);
    o1 = make_ushort4(tmp[4], tmp[5], tmp[6], tmp[7]);
  } else {
    o0 = make_ushort4(0, 0, 0, 0);
    o1 = make_ushort4(0, 0, 0, 0);
  }
  *(ushort4*)(P + off) = o0;
  *(ushort4*)(P + off + 4) = o1;
}

// ---------------------------------------------------------------------------
extern "C" void kernel_launch(void* const* d_in, const int* in_sizes, int n_in,
                              void* d_out, int out_size, void* d_ws, size_t ws_size,
                              hipStream_t stream) {
  (void)in_sizes; (void)n_in; (void)out_size; (void)ws_size;
  const float* x     = (const float*)d_in[0];
  const int*   l     = (const int*)d_in[1];
  const float* Wq    = (const float*)d_in[2];
  const float* Wk    = (const float*)d_in[3];
  const float* Wv    = (const float*)d_in[4];
  const float* Wo    = (const float*)d_in[5];
  const float* bo    = (const float*)d_in[6];
  const float* gamma = (const float*)d_in[7];
  const float* beta  = (const float*)d_in[8];

  char* ws = (char*)d_ws;
  const size_t MiB = 1024 * 1024;
  u16* xn  = (u16*)(ws);             // 16 MiB (x_norm bf16); later reused for y
  u16* wqb = (u16*)(ws + 16 * MiB);  // 2 MiB each
  u16* wkb = (u16*)(ws + 18 * MiB);
  u16* wvb = (u16*)(ws + 20 * MiB);
  u16* wob = (u16*)(ws + 22 * MiB);
  u16* Qb  = (u16*)(ws + 24 * MiB);  // 16 MiB ; P (32 MiB) later spans Q..K
  u16* Kb  = (u16*)(ws + 40 * MiB);  // 16 MiB
  u16* Vt  = (u16*)(ws + 56 * MiB);  // 16 MiB (V^T per batch: [D][T])
  float* mb  = (float*)(ws + 72 * MiB);
  float* rzb = (float*)(ws + 72 * MiB + 32 * 1024);
  u16* Pb = Qb;
  u16* yb = xn;
  __half* S = (__half*)d_out;        // d_out doubles as the 33.5 MiB score scratch
  float* outp = (float*)d_out;

  const long TD = (long)T_SEQ * DIM, TT = (long)T_SEQ * T_SEQ, DT = (long)DIM * T_SEQ;

  ln_kernel<<<NB * T_SEQ, 256, 0, stream>>>(x, gamma, beta, xn);
  wcvt<<<1024, 256, 0, stream>>>(Wq, wqb);
  wcvt<<<1024, 256, 0, stream>>>(Wk, wkb);
  wcvt<<<1024, 256, 0, stream>>>(Wv, wvb);
  wcvt<<<1024, 256, 0, stream>>>(Wo, wob);

  // Q = xn @ Wq^T   [8192,1024]
  gemm_bt<0><<<dim3(8, 64, 1), 256, 0, stream>>>(xn, wqb, Qb, DIM, DIM, DIM, DIM, 0, 0, 0, nullptr, 0, 0.f);
  // K = xn @ Wk^T
  gemm_bt<0><<<dim3(8, 64, 1), 256, 0, stream>>>(xn, wkb, Kb, DIM, DIM, DIM, DIM, 0, 0, 0, nullptr, 0, 0.f);
  // V^T[b] = Wv_bf @ xn_b^T   [1024, 2048] per batch
  gemm_bt<0><<<dim3(16, 8, NB), 256, 0, stream>>>(wvb, xn, Vt, DIM, DIM, DIM, T_SEQ, 0, TD, DT, nullptr, 0, 0.f);
  // S[b] = (Q_b @ K_b^T) * scale  -> fp16, into d_out scratch
  gemm_bt<1><<<dim3(16, 16, NB), 256, 0, stream>>>(Qb, Kb, S, DIM, DIM, DIM, T_SEQ, TD, TD, TT, nullptr, 0, 0.03125f);
  // column max / 1-over-sum over valid rows
  colreduce<<<dim3(T_SEQ / 256, NB), 256, 0, stream>>>(S, l, mb, rzb);
  // P = exp(S-m)*rz (bf16), zero for masked rows
  pbuild<<<NB * T_SEQ, 256, 0, stream>>>(S, l, mb, rzb, Pb);
  // y[b] = x_b + P_b @ Vt_b^T   [2048,1024] bf16
  gemm_bt<2><<<dim3(8, 16, NB), 256, 0, stream>>>(Pb, Vt, yb, T_SEQ, T_SEQ, T_SEQ, DIM, TT, DT, TD, x, TD, 0.f);
  // out = relu(y @ Wo^T + bo)   f32
  gemm_bt<3><<<dim3(8, 64, 1), 256, 0, stream>>>(yb, wob, outp, DIM, DIM, DIM, DIM, 0, 0, 0, bo, 0, 0.f);
}

// Round 2
// 299.240 us; speedup vs baseline: 2.5751x; 2.5751x over previous
//
#include <hip/hip_runtime.h>
#include <hip/hip_fp16.h>

typedef unsigned short u16;
typedef __attribute__((ext_vector_type(8))) short bf16x8;
typedef __attribute__((ext_vector_type(4))) float f32x4;

#define T_SEQ 2048
#define DIM 1024
#define NB 4
#define NCH 16        // row chunks for column-softmax reduce
#define RCHUNK (T_SEQ / NCH)

__device__ __forceinline__ u16 f2bf(float f) {
  union { float f; unsigned u; } c; c.f = f;
  unsigned r = c.u + 0x7fffu + ((c.u >> 16) & 1u);
  return (u16)(r >> 16);
}

__device__ __forceinline__ void gload_lds16(const void* g, void* l) {
  __builtin_amdgcn_global_load_lds((const __attribute__((address_space(1))) void*)g,
                                   (__attribute__((address_space(3))) void*)l, 16, 0, 0);
}

// ---------------- LayerNorm: x (f32) -> x_norm (bf16) ----------------
__global__ __launch_bounds__(256) void ln_kernel(const float* __restrict__ x,
                                                 const float* __restrict__ gamma,
                                                 const float* __restrict__ beta,
                                                 u16* __restrict__ xn) {
  const int row = blockIdx.x;
  const int tid = threadIdx.x;
  const float4 v = *(const float4*)(x + (size_t)row * DIM + tid * 4);
  float s  = v.x + v.y + v.z + v.w;
  float ss = v.x * v.x + v.y * v.y + v.z * v.z + v.w * v.w;
#pragma unroll
  for (int o = 32; o > 0; o >>= 1) { s += __shfl_down(s, o); ss += __shfl_down(ss, o); }
  __shared__ float rs[4], rss[4];
  const int wid = tid >> 6, lane = tid & 63;
  if (lane == 0) { rs[wid] = s; rss[wid] = ss; }
  __syncthreads();
  s  = rs[0] + rs[1] + rs[2] + rs[3];
  ss = rss[0] + rss[1] + rss[2] + rss[3];
  const float mu = s * (1.f / DIM);
  const float var = ss * (1.f / DIM) - mu * mu;
  const float rstd = rsqrtf(var + 1e-5f);
  const float4 g  = *(const float4*)(gamma + tid * 4);
  const float4 be = *(const float4*)(beta + tid * 4);
  ushort4 o;
  o.x = f2bf((v.x - mu) * rstd * g.x + be.x);
  o.y = f2bf((v.y - mu) * rstd * g.y + be.y);
  o.z = f2bf((v.z - mu) * rstd * g.z + be.z);
  o.w = f2bf((v.w - mu) * rstd * g.w + be.w);
  *(ushort4*)(xn + (size_t)row * DIM + tid * 4) = o;
}

// ---------------- f32 -> bf16 weight convert ----------------
__global__ __launch_bounds__(256) void wcvt(const float* __restrict__ w, u16* __restrict__ o) {
  const size_t t = (size_t)blockIdx.x * 256 + threadIdx.x;
  const float4 v = *(const float4*)(w + t * 4);
  ushort4 u; u.x = f2bf(v.x); u.y = f2bf(v.y); u.z = f2bf(v.z); u.w = f2bf(v.w);
  *(ushort4*)(o + t * 4) = u;
}

// ---------------- GEMM: C[M,N] = A[M,K] * B[N,K]^T  (bf16 in, fp32 acc) ----
// EPI 0: store bf16          EPI 1: store fp16, *scale
// EPI 2: store bf16, + aux residual (f32, batched)   EPI 3: store f32, +bias[col], relu
template <int EPI>
__global__ __launch_bounds__(256) void gemm_bt(
    const u16* __restrict__ A, const u16* __restrict__ B, void* __restrict__ Cv,
    int K, int lda, int ldb, int ldc,
    long sA, long sB, long sC,
    const float* __restrict__ aux, long sAux, float scale) {
  __shared__ __align__(16) u16 As[128 * 64];
  __shared__ __align__(16) u16 Bs[128 * 64];
  const int bz = blockIdx.z;
  const u16* Ab = A + (size_t)bz * sA;
  const u16* Bb = B + (size_t)bz * sB;
  const int tileM = blockIdx.y * 128;
  const int tileN = blockIdx.x * 128;
  const int tid = threadIdx.x;
  const int lane = tid & 63;
  const int wid = tid >> 6;
  const int wm = wid >> 1, wn = wid & 1;

  f32x4 acc[4][4] = {};

  for (int k0 = 0; k0 < K; k0 += 64) {
#pragma unroll
    for (int r = 0; r < 4; ++r) {
      const int e = r * 2048 + tid * 8;
      const int row = e >> 6, kk = e & 63;
      gload_lds16(Ab + (size_t)(tileM + row) * lda + (k0 + kk), &As[e]);
      gload_lds16(Bb + (size_t)(tileN + row) * ldb + (k0 + kk), &Bs[e]);
    }
    __syncthreads();
#pragma unroll
    for (int kk = 0; kk < 64; kk += 32) {
      bf16x8 af[4], bh[4];
      const int koff = kk + ((lane >> 4) << 3);
#pragma unroll
      for (int i = 0; i < 4; ++i) {
        af[i] = *(const bf16x8*)&As[(wm * 64 + i * 16 + (lane & 15)) * 64 + koff];
        bh[i] = *(const bf16x8*)&Bs[(wn * 64 + i * 16 + (lane & 15)) * 64 + koff];
      }
#pragma unroll
      for (int i = 0; i < 4; ++i)
#pragma unroll
        for (int j = 0; j < 4; ++j)
          acc[i][j] = __builtin_amdgcn_mfma_f32_16x16x32_bf16(af[i], bh[j], acc[i][j], 0, 0, 0);
    }
    __syncthreads();
  }

  const int r0 = tileM + wm * 64 + ((lane >> 4) << 2);
  const int c0 = tileN + wn * 64 + (lane & 15);
#pragma unroll
  for (int i = 0; i < 4; ++i)
#pragma unroll
    for (int j = 0; j < 4; ++j)
#pragma unroll
      for (int r = 0; r < 4; ++r) {
        const int row = r0 + i * 16 + r, col = c0 + j * 16;
        const size_t idx = (size_t)row * ldc + col;
        float v = acc[i][j][r];
        if constexpr (EPI == 0) {
          ((u16*)Cv + (size_t)bz * sC)[idx] = f2bf(v);
        } else if constexpr (EPI == 1) {
          ((__half*)Cv + (size_t)bz * sC)[idx] = __float2half(v * scale);
        } else if constexpr (EPI == 2) {
          v += (aux + (size_t)bz * sAux)[idx];
          ((u16*)Cv + (size_t)bz * sC)[idx] = f2bf(v);
        } else {
          v += aux[col];
          ((float*)Cv + (size_t)bz * sC)[idx] = fmaxf(v, 0.f);
        }
      }
}

// ------- pass 1: per-column (axis=i) partial max & sumexp over a row chunk --
__global__ __launch_bounds__(256) void colreduce_part(const __half* __restrict__ S,
                                                      const int* __restrict__ l,
                                                      float* __restrict__ mp,
                                                      float* __restrict__ zp) {
  const int b = blockIdx.y;
  const int ch = blockIdx.z;
  const int j = blockIdx.x * 256 + threadIdx.x;
  const __half* Sb = S + (size_t)b * T_SEQ * T_SEQ;
  const int L = l[b];
  const int i0 = ch * RCHUNK;
  const int i1 = min(i0 + RCHUNK, L);

  // 4 independent online-softmax chains for ILP / latency hiding
  float mm[4] = {-1e30f, -1e30f, -1e30f, -1e30f};
  float zz[4] = {0.f, 0.f, 0.f, 0.f};
  for (int i = i0; i < i1; i += 4) {
#pragma unroll
    for (int u = 0; u < 4; ++u) {
      const int ii = i + u;
      if (ii < i1) {
        const float s = __half2float(Sb[(size_t)ii * T_SEQ + j]);
        if (s > mm[u]) { zz[u] *= __expf(mm[u] - s); mm[u] = s; zz[u] += 1.f; }
        else           { zz[u] += __expf(s - mm[u]); }
      }
    }
  }
  // merge the 4 chains
  float M = fmaxf(fmaxf(mm[0], mm[1]), fmaxf(mm[2], mm[3]));
  float Z = 0.f;
#pragma unroll
  for (int u = 0; u < 4; ++u) Z += zz[u] * __expf(mm[u] - M);

  const size_t o = ((size_t)ch * NB + b) * T_SEQ + j;
  mp[o] = M;
  zp[o] = Z;
}

// ------- pass 2: combine NCH partials per column -> m, 1/Z ------------------
__global__ __launch_bounds__(256) void colreduce_comb(const float* __restrict__ mp,
                                                      const float* __restrict__ zp,
                                                      float* __restrict__ m,
                                                      float* __restrict__ rz) {
  const int b = blockIdx.y;
  const int j = blockIdx.x * 256 + threadIdx.x;
  float M = -1e30f, Z = 0.f;
#pragma unroll
  for (int c = 0; c < NCH; ++c) {
    const size_t o = ((size_t)c * NB + b) * T_SEQ + j;
    const float mc = mp[o], zc = zp[o];
    const float nm = fmaxf(M, mc);
    Z = Z * __expf(M - nm) + zc * __expf(mc - nm);
    M = nm;
  }
  m[b * T_SEQ + j] = M;
  rz[b * T_SEQ + j] = 1.f / Z;
}

// ---------------- P = exp(S - m) / Z  (bf16, row-masked) -------------------
__global__ __launch_bounds__(256) void pbuild(const __half* __restrict__ S,
                                              const int* __restrict__ l,
                                              const float* __restrict__ m,
                                              const float* __restrict__ rz,
                                              u16* __restrict__ P) {
  const int b = blockIdx.x >> 11;
  const int i = blockIdx.x & (T_SEQ - 1);
  const int j0 = threadIdx.x * 8;
  const size_t off = ((size_t)blockIdx.x << 11) + j0;
  ushort4 o0, o1;
  if (i < l[b]) {
    const __half* sp = S + off;
    const float* mp = m + b * T_SEQ + j0;
    const float* zp = rz + b * T_SEQ + j0;
    u16 tmp[8];
#pragma unroll
    for (int t = 0; t < 8; ++t)
      tmp[t] = f2bf(__expf(__half2float(sp[t]) - mp[t]) * zp[t]);
    o0 = make_ushort4(tmp[0], tmp[1], tmp[2], tmp[3]);
    o1 = make_ushort4(tmp[4], tmp[5], tmp[6], tmp[7]);
  } else {
    o0 = make_ushort4(0, 0, 0, 0);
    o1 = make_ushort4(0, 0, 0, 0);
  }
  *(ushort4*)(P + off) = o0;
  *(ushort4*)(P + off + 4) = o1;
}

// ---------------------------------------------------------------------------
extern "C" void kernel_launch(void* const* d_in, const int* in_sizes, int n_in,
                              void* d_out, int out_size, void* d_ws, size_t ws_size,
                              hipStream_t stream) {
  (void)in_sizes; (void)n_in; (void)out_size; (void)ws_size;
  const float* x     = (const float*)d_in[0];
  const int*   l     = (const int*)d_in[1];
  const float* Wq    = (const float*)d_in[2];
  const float* Wk    = (const float*)d_in[3];
  const float* Wv    = (const float*)d_in[4];
  const float* Wo    = (const float*)d_in[5];
  const float* bo    = (const float*)d_in[6];
  const float* gamma = (const float*)d_in[7];
  const float* beta  = (const float*)d_in[8];

  char* ws = (char*)d_ws;
  const size_t MiB = 1024 * 1024;
  u16* xn  = (u16*)(ws);             // 16 MiB (x_norm bf16); later reused for y
  u16* wqb = (u16*)(ws + 16 * MiB);  // 2 MiB each
  u16* wkb = (u16*)(ws + 18 * MiB);
  u16* wvb = (u16*)(ws + 20 * MiB);
  u16* wob = (u16*)(ws + 22 * MiB);
  u16* Qb  = (u16*)(ws + 24 * MiB);  // 16 MiB ; P (32 MiB) later spans Q..K
  u16* Kb  = (u16*)(ws + 40 * MiB);  // 16 MiB
  u16* Vt  = (u16*)(ws + 56 * MiB);  // 16 MiB (V^T per batch: [D][T])
  float* mb  = (float*)(ws + 72 * MiB);
  float* rzb = (float*)(ws + 72 * MiB + 32 * 1024);
  // softmax partials live in the dead K region (K consumed by S-GEMM before
  // colreduce_part runs; pbuild overwrites it only after colreduce_comb read it)
  float* mpart = (float*)(ws + 40 * MiB);                 // 512 KiB
  float* zpart = (float*)(ws + 40 * MiB + 512 * 1024);    // 512 KiB
  u16* Pb = Qb;
  u16* yb = xn;
  __half* S = (__half*)d_out;        // d_out doubles as the 33.5 MiB score scratch
  float* outp = (float*)d_out;

  const long TD = (long)T_SEQ * DIM, TT = (long)T_SEQ * T_SEQ, DT = (long)DIM * T_SEQ;

  ln_kernel<<<NB * T_SEQ, 256, 0, stream>>>(x, gamma, beta, xn);
  wcvt<<<1024, 256, 0, stream>>>(Wq, wqb);
  wcvt<<<1024, 256, 0, stream>>>(Wk, wkb);
  wcvt<<<1024, 256, 0, stream>>>(Wv, wvb);
  wcvt<<<1024, 256, 0, stream>>>(Wo, wob);

  // Q = xn @ Wq^T   [8192,1024]
  gemm_bt<0><<<dim3(8, 64, 1), 256, 0, stream>>>(xn, wqb, Qb, DIM, DIM, DIM, DIM, 0, 0, 0, nullptr, 0, 0.f);
  // K = xn @ Wk^T
  gemm_bt<0><<<dim3(8, 64, 1), 256, 0, stream>>>(xn, wkb, Kb, DIM, DIM, DIM, DIM, 0, 0, 0, nullptr, 0, 0.f);
  // V^T[b] = Wv_bf @ xn_b^T   [1024, 2048] per batch
  gemm_bt<0><<<dim3(16, 8, NB), 256, 0, stream>>>(wvb, xn, Vt, DIM, DIM, DIM, T_SEQ, 0, TD, DT, nullptr, 0, 0.f);
  // S[b] = (Q_b @ K_b^T) * scale  -> fp16, into d_out scratch
  gemm_bt<1><<<dim3(16, 16, NB), 256, 0, stream>>>(Qb, Kb, S, DIM, DIM, DIM, T_SEQ, TD, TD, TT, nullptr, 0, 0.03125f);
  // column max / sumexp: chunked partials then combine
  colreduce_part<<<dim3(T_SEQ / 256, NB, NCH), 256, 0, stream>>>(S, l, mpart, zpart);
  colreduce_comb<<<dim3(T_SEQ / 256, NB), 256, 0, stream>>>(mpart, zpart, mb, rzb);
  // P = exp(S-m)*rz (bf16), zero for masked rows
  pbuild<<<NB * T_SEQ, 256, 0, stream>>>(S, l, mb, rzb, Pb);
  // y[b] = x_b + P_b @ Vt_b^T   [2048,1024] bf16
  gemm_bt<2><<<dim3(8, 16, NB), 256, 0, stream>>>(Pb, Vt, yb, T_SEQ, T_SEQ, T_SEQ, DIM, TT, DT, TD, x, TD, 0.f);
  // out = relu(y @ Wo^T + bo)   f32
  gemm_bt<3><<<dim3(8, 64, 1), 256, 0, stream>>>(yb, wob, outp, DIM, DIM, DIM, DIM, 0, 0, 0, bo, 0, 0.f);
}

// Round 3
// 257.284 us; speedup vs baseline: 2.9950x; 1.1631x over previous
//
#include <hip/hip_runtime.h>
#include <hip/hip_fp16.h>

typedef unsigned short u16;
typedef __attribute__((ext_vector_type(8))) short bf16x8;
typedef __attribute__((ext_vector_type(4))) float f32x4;

#define T_SEQ 2048
#define DIM 1024
#define NB 4
#define NCH 16        // row chunks for column-softmax reduce
#define RCHUNK (T_SEQ / NCH)

__device__ __forceinline__ u16 f2bf(float f) {
  union { float f; unsigned u; } c; c.f = f;
  unsigned r = c.u + 0x7fffu + ((c.u >> 16) & 1u);
  return (u16)(r >> 16);
}

__device__ __forceinline__ void gload_lds16(const void* g, void* l) {
  __builtin_amdgcn_global_load_lds((const __attribute__((address_space(1))) void*)g,
                                   (__attribute__((address_space(3))) void*)l, 16, 0, 0);
}

#define SBAR() asm volatile("s_barrier" ::: "memory")

// ---------------- LayerNorm: x (f32) -> x_norm (bf16) ----------------
__global__ __launch_bounds__(256) void ln_kernel(const float* __restrict__ x,
                                                 const float* __restrict__ gamma,
                                                 const float* __restrict__ beta,
                                                 u16* __restrict__ xn) {
  const int row = blockIdx.x;
  const int tid = threadIdx.x;
  const float4 v = *(const float4*)(x + (size_t)row * DIM + tid * 4);
  float s  = v.x + v.y + v.z + v.w;
  float ss = v.x * v.x + v.y * v.y + v.z * v.z + v.w * v.w;
#pragma unroll
  for (int o = 32; o > 0; o >>= 1) { s += __shfl_down(s, o); ss += __shfl_down(ss, o); }
  __shared__ float rs[4], rss[4];
  const int wid = tid >> 6, lane = tid & 63;
  if (lane == 0) { rs[wid] = s; rss[wid] = ss; }
  __syncthreads();
  s  = rs[0] + rs[1] + rs[2] + rs[3];
  ss = rss[0] + rss[1] + rss[2] + rss[3];
  const float mu = s * (1.f / DIM);
  const float var = ss * (1.f / DIM) - mu * mu;
  const float rstd = rsqrtf(var + 1e-5f);
  const float4 g  = *(const float4*)(gamma + tid * 4);
  const float4 be = *(const float4*)(beta + tid * 4);
  ushort4 o;
  o.x = f2bf((v.x - mu) * rstd * g.x + be.x);
  o.y = f2bf((v.y - mu) * rstd * g.y + be.y);
  o.z = f2bf((v.z - mu) * rstd * g.z + be.z);
  o.w = f2bf((v.w - mu) * rstd * g.w + be.w);
  *(ushort4*)(xn + (size_t)row * DIM + tid * 4) = o;
}

// ---------------- f32 -> bf16 weight convert, all 4 weights in one launch ---
__global__ __launch_bounds__(256) void wcvt4(const float* __restrict__ wq,
                                             const float* __restrict__ wk,
                                             const float* __restrict__ wv,
                                             const float* __restrict__ wo,
                                             u16* __restrict__ dqk,
                                             u16* __restrict__ dv,
                                             u16* __restrict__ dw) {
  const int sel = blockIdx.x >> 10;                      // 1024 blocks per weight
  const size_t t = (size_t)(blockIdx.x & 1023) * 256 + threadIdx.x;
  const float* w = (sel == 0) ? wq : (sel == 1) ? wk : (sel == 2) ? wv : wo;
  u16* d = (sel == 0) ? dqk : (sel == 1) ? (dqk + 1048576) : (sel == 2) ? dv : dw;
  const float4 v = *(const float4*)(w + t * 4);
  ushort4 u; u.x = f2bf(v.x); u.y = f2bf(v.y); u.z = f2bf(v.z); u.w = f2bf(v.w);
  *(ushort4*)(d + t * 4) = u;
}

// ==== GEMM: C[M,N] = A[M,K] * B[N,K]^T,  BM=128 BN=256 BK=64, 512 thr ======
// Ring-of-3 LDS, counted vmcnt(6) pipeline, XOR-swizzled slots, setprio MFMA.
// EPI 0: store bf16          EPI 1: store fp16, *scale
// EPI 2: store bf16, + aux residual (f32, batched)   EPI 3: store f32, +bias[col], relu
template <int EPI>
__global__ __launch_bounds__(512, 2) void gemm_bt(
    const u16* __restrict__ A, const u16* __restrict__ B, void* __restrict__ Cv,
    int K, int lda, int ldb, int ldc,
    long sA, long sB, long sC,
    const float* __restrict__ aux, long sAux, float scale) {
  __shared__ __align__(16) u16 As[3][128 * 64];   // 3 x 16 KiB
  __shared__ __align__(16) u16 Bs[3][256 * 64];   // 3 x 32 KiB
  const int bz = blockIdx.z;
  const u16* Ab = A + (size_t)bz * sA;
  const u16* Bb = B + (size_t)bz * sB;
  const int tileM = blockIdx.y * 128;
  const int tileN = blockIdx.x * 256;
  const int t = threadIdx.x;
  const int lane = t & 63;
  const int wid = t >> 6;
  const int wm = wid >> 2, wn = wid & 3;          // 2 x 4 waves

  // ---- staging source offsets (elements). LDS layout [row][64] with 16B
  // slots swizzled: slot s holds k-chunk (s ^ (row&7)). gload_lds writes
  // linearly, so the SOURCE address carries the swizzle (rule #21).
  const int srow = t >> 3;                        // 0..63 within quarter
  const int swzc = ((t & 7) ^ (srow & 7)) * 8;    // swizzled k-chunk start
  const size_t aoff0 = (size_t)(tileM + srow) * lda + swzc;
  const size_t aoff1 = (size_t)(tileM + 64 + srow) * lda + swzc;
  const size_t boff0 = (size_t)(tileN + srow) * ldb + swzc;
  const size_t boff1 = (size_t)(tileN + 64 + srow) * ldb + swzc;
  const size_t boff2 = (size_t)(tileN + 128 + srow) * ldb + swzc;
  const size_t boff3 = (size_t)(tileN + 192 + srow) * ldb + swzc;

  // ---- fragment-read constants
  const int frow = lane & 15;
  const int r7 = lane & 7;
  const int kg = lane >> 4;                       // 0..3

  f32x4 acc[4][4] = {};
  const int NT = K >> 6;

  // prologue: stage tiles 0 and 1 (6 loads each)
  {
    gload_lds16(Ab + aoff0, &As[0][t * 8]);
    gload_lds16(Ab + aoff1, &As[0][4096 + t * 8]);
    gload_lds16(Bb + boff0, &Bs[0][t * 8]);
    gload_lds16(Bb + boff1, &Bs[0][4096 + t * 8]);
    gload_lds16(Bb + boff2, &Bs[0][8192 + t * 8]);
    gload_lds16(Bb + boff3, &Bs[0][12288 + t * 8]);
    gload_lds16(Ab + aoff0 + 64, &As[1][t * 8]);
    gload_lds16(Ab + aoff1 + 64, &As[1][4096 + t * 8]);
    gload_lds16(Bb + boff0 + 64, &Bs[1][t * 8]);
    gload_lds16(Bb + boff1 + 64, &Bs[1][4096 + t * 8]);
    gload_lds16(Bb + boff2 + 64, &Bs[1][8192 + t * 8]);
    gload_lds16(Bb + boff3 + 64, &Bs[1][12288 + t * 8]);
  }
  asm volatile("s_waitcnt vmcnt(6)" ::: "memory");  // tile 0 landed (all waves' after barrier)
  SBAR();

  int cur = 0;
  for (int tau = 0; tau < NT; ++tau) {
    const int nslot = (cur == 0) ? 2 : (cur - 1);   // (cur+2) % 3
    const bool st = (tau + 2 < NT);
    const size_t k0 = (size_t)(tau + 2) * 64;

    // ---------- phase 1: k-slice 0 ----------
    bf16x8 a0[4], b0[4];
#pragma unroll
    for (int i = 0; i < 4; ++i)
      a0[i] = *(const bf16x8*)&As[cur][(wm * 64 + i * 16 + frow) * 64 + ((kg ^ r7) << 3)];
#pragma unroll
    for (int j = 0; j < 4; ++j)
      b0[j] = *(const bf16x8*)&Bs[cur][(wn * 64 + j * 16 + frow) * 64 + ((kg ^ r7) << 3)];
    if (st) {
      gload_lds16(Ab + aoff0 + k0, &As[nslot][t * 8]);
      gload_lds16(Ab + aoff1 + k0, &As[nslot][4096 + t * 8]);
      gload_lds16(Bb + boff0 + k0, &Bs[nslot][t * 8]);
    }
    SBAR();
    __builtin_amdgcn_s_setprio(1);
#pragma unroll
    for (int i = 0; i < 4; ++i)
#pragma unroll
      for (int j = 0; j < 4; ++j)
        acc[i][j] = __builtin_amdgcn_mfma_f32_16x16x32_bf16(a0[i], b0[j], acc[i][j], 0, 0, 0);
    __builtin_amdgcn_s_setprio(0);
    SBAR();

    // ---------- phase 2: k-slice 1 ----------
    bf16x8 a1[4], b1[4];
#pragma unroll
    for (int i = 0; i < 4; ++i)
      a1[i] = *(const bf16x8*)&As[cur][(wm * 64 + i * 16 + frow) * 64 + (((4 + kg) ^ r7) << 3)];
#pragma unroll
    for (int j = 0; j < 4; ++j)
      b1[j] = *(const bf16x8*)&Bs[cur][(wn * 64 + j * 16 + frow) * 64 + (((4 + kg) ^ r7) << 3)];
    if (st) {
      gload_lds16(Bb + boff1 + k0, &Bs[nslot][4096 + t * 8]);
      gload_lds16(Bb + boff2 + k0, &Bs[nslot][8192 + t * 8]);
      gload_lds16(Bb + boff3 + k0, &Bs[nslot][12288 + t * 8]);
    }
    SBAR();
    __builtin_amdgcn_s_setprio(1);
#pragma unroll
    for (int i = 0; i < 4; ++i)
#pragma unroll
      for (int j = 0; j < 4; ++j)
        acc[i][j] = __builtin_amdgcn_mfma_f32_16x16x32_bf16(a1[i], b1[j], acc[i][j], 0, 0, 0);
    __builtin_amdgcn_s_setprio(0);
    // counted drain: retire stage(tau+1); stage(tau+2)'s 6 loads stay in flight
    if (st) asm volatile("s_waitcnt vmcnt(6)" ::: "memory");
    else    asm volatile("s_waitcnt vmcnt(0)" ::: "memory");
    SBAR();
    cur = (cur == 2) ? 0 : (cur + 1);
  }

  // ---------- epilogue ----------
  const int r0 = tileM + wm * 64 + (kg << 2);
  const int c0 = tileN + wn * 64 + frow;
#pragma unroll
  for (int i = 0; i < 4; ++i)
#pragma unroll
    for (int j = 0; j < 4; ++j)
#pragma unroll
      for (int r = 0; r < 4; ++r) {
        const int row = r0 + i * 16 + r, col = c0 + j * 16;
        const size_t idx = (size_t)row * ldc + col;
        float v = acc[i][j][r];
        if constexpr (EPI == 0) {
          ((u16*)Cv + (size_t)bz * sC)[idx] = f2bf(v);
        } else if constexpr (EPI == 1) {
          ((__half*)Cv + (size_t)bz * sC)[idx] = __float2half(v * scale);
        } else if constexpr (EPI == 2) {
          v += (aux + (size_t)bz * sAux)[idx];
          ((u16*)Cv + (size_t)bz * sC)[idx] = f2bf(v);
        } else {
          v += aux[col];
          ((float*)Cv + (size_t)bz * sC)[idx] = fmaxf(v, 0.f);
        }
      }
}

// ------- pass 1: per-column (axis=i) partial max & sumexp over a row chunk --
__global__ __launch_bounds__(256) void colreduce_part(const __half* __restrict__ S,
                                                      const int* __restrict__ l,
                                                      float* __restrict__ mp,
                                                      float* __restrict__ zp) {
  const int b = blockIdx.y;
  const int ch = blockIdx.z;
  const int j = blockIdx.x * 256 + threadIdx.x;
  const __half* Sb = S + (size_t)b * T_SEQ * T_SEQ;
  const int L = l[b];
  const int i0 = ch * RCHUNK;
  const int i1 = min(i0 + RCHUNK, L);

  float mm[4] = {-1e30f, -1e30f, -1e30f, -1e30f};
  float zz[4] = {0.f, 0.f, 0.f, 0.f};
  for (int i = i0; i < i1; i += 4) {
#pragma unroll
    for (int u = 0; u < 4; ++u) {
      const int ii = i + u;
      if (ii < i1) {
        const float s = __half2float(Sb[(size_t)ii * T_SEQ + j]);
        if (s > mm[u]) { zz[u] *= __expf(mm[u] - s); mm[u] = s; zz[u] += 1.f; }
        else           { zz[u] += __expf(s - mm[u]); }
      }
    }
  }
  float M = fmaxf(fmaxf(mm[0], mm[1]), fmaxf(mm[2], mm[3]));
  float Z = 0.f;
#pragma unroll
  for (int u = 0; u < 4; ++u) Z += zz[u] * __expf(mm[u] - M);

  const size_t o = ((size_t)ch * NB + b) * T_SEQ + j;
  mp[o] = M;
  zp[o] = Z;
}

// ------- pass 2: combine NCH partials per column -> m, 1/Z ------------------
__global__ __launch_bounds__(256) void colreduce_comb(const float* __restrict__ mp,
                                                      const float* __restrict__ zp,
                                                      float* __restrict__ m,
                                                      float* __restrict__ rz) {
  const int b = blockIdx.y;
  const int j = blockIdx.x * 256 + threadIdx.x;
  float M = -1e30f, Z = 0.f;
#pragma unroll
  for (int c = 0; c < NCH; ++c) {
    const size_t o = ((size_t)c * NB + b) * T_SEQ + j;
    const float mc = mp[o], zc = zp[o];
    const float nm = fmaxf(M, mc);
    Z = Z * __expf(M - nm) + zc * __expf(mc - nm);
    M = nm;
  }
  m[b * T_SEQ + j] = M;
  rz[b * T_SEQ + j] = 1.f / Z;
}

// ---------------- P = exp(S - m) / Z  (bf16, row-masked) -------------------
__global__ __launch_bounds__(256) void pbuild(const __half* __restrict__ S,
                                              const int* __restrict__ l,
                                              const float* __restrict__ m,
                                              const float* __restrict__ rz,
                                              u16* __restrict__ P) {
  const int b = blockIdx.x >> 11;
  const int i = blockIdx.x & (T_SEQ - 1);
  const int j0 = threadIdx.x * 8;
  const size_t off = ((size_t)blockIdx.x << 11) + j0;
  ushort4 o0, o1;
  if (i < l[b]) {
    const __half* sp = S + off;
    const float* mp = m + b * T_SEQ + j0;
    const float* zp = rz + b * T_SEQ + j0;
    u16 tmp[8];
#pragma unroll
    for (int t = 0; t < 8; ++t)
      tmp[t] = f2bf(__expf(__half2float(sp[t]) - mp[t]) * zp[t]);
    o0 = make_ushort4(tmp[0], tmp[1], tmp[2], tmp[3]);
    o1 = make_ushort4(tmp[4], tmp[5], tmp[6], tmp[7]);
  } else {
    o0 = make_ushort4(0, 0, 0, 0);
    o1 = make_ushort4(0, 0, 0, 0);
  }
  *(ushort4*)(P + off) = o0;
  *(ushort4*)(P + off + 4) = o1;
}

// ---------------------------------------------------------------------------
extern "C" void kernel_launch(void* const* d_in, const int* in_sizes, int n_in,
                              void* d_out, int out_size, void* d_ws, size_t ws_size,
                              hipStream_t stream) {
  (void)in_sizes; (void)n_in; (void)out_size; (void)ws_size;
  const float* x     = (const float*)d_in[0];
  const int*   l     = (const int*)d_in[1];
  const float* Wq    = (const float*)d_in[2];
  const float* Wk    = (const float*)d_in[3];
  const float* Wv    = (const float*)d_in[4];
  const float* Wo    = (const float*)d_in[5];
  const float* bo    = (const float*)d_in[6];
  const float* gamma = (const float*)d_in[7];
  const float* beta  = (const float*)d_in[8];

  char* ws = (char*)d_ws;
  const size_t MiB = 1024 * 1024;
  u16* xn   = (u16*)(ws);             // 16 MiB x_norm; later reused as y
  u16* wqkb = (u16*)(ws + 16 * MiB);  // 4 MiB: Wq rows then Wk rows (concat)
  u16* wvb  = (u16*)(ws + 20 * MiB);  // 2 MiB; reused for softmax partials
  u16* wob  = (u16*)(ws + 22 * MiB);  // 2 MiB
  u16* QKb  = (u16*)(ws + 24 * MiB);  // 32 MiB: [8192][2048] Q|K; reused as P
  u16* Vt   = (u16*)(ws + 56 * MiB);  // 16 MiB: [1024][8192] V^T (all batches)
  float* mpart = (float*)(ws + 20 * MiB);                // 512 KiB (over wvb, dead)
  float* zpart = (float*)(ws + 20 * MiB + 512 * 1024);   // 512 KiB
  float* mb  = (float*)(ws + 72 * MiB);
  float* rzb = (float*)(ws + 72 * MiB + 32 * 1024);
  u16* Pb = QKb;                      // P overwrites dead Q|K
  u16* yb = xn;
  __half* S = (__half*)d_out;         // d_out doubles as the 32 MiB score scratch
  float* outp = (float*)d_out;

  const long TD = (long)T_SEQ * DIM, TT = (long)T_SEQ * T_SEQ;
  const long TQK = (long)T_SEQ * 2048;   // per-batch stride in QKb

  ln_kernel<<<NB * T_SEQ, 256, 0, stream>>>(x, gamma, beta, xn);
  wcvt4<<<4096, 256, 0, stream>>>(Wq, Wk, Wv, Wo, wqkb, wvb, wob);

  // Q|K = xn @ [Wq;Wk]^T   [8192,2048]
  gemm_bt<0><<<dim3(2048 / 256, 8192 / 128, 1), 512, 0, stream>>>(
      xn, wqkb, QKb, DIM, DIM, DIM, 2048, 0, 0, 0, nullptr, 0, 0.f);
  // V^T = Wv_bf @ xn^T   [1024, 8192]
  gemm_bt<0><<<dim3(8192 / 256, 1024 / 128, 1), 512, 0, stream>>>(
      wvb, xn, Vt, DIM, DIM, DIM, 8192, 0, 0, 0, nullptr, 0, 0.f);
  // S[b] = (Q_b @ K_b^T) * scale  -> fp16 into d_out scratch
  gemm_bt<1><<<dim3(2048 / 256, 2048 / 128, NB), 512, 0, stream>>>(
      QKb, QKb + 1024, S, DIM, 2048, 2048, T_SEQ, TQK, TQK, TT, nullptr, 0, 0.03125f);
  // column max / sumexp: chunked partials then combine
  colreduce_part<<<dim3(T_SEQ / 256, NB, NCH), 256, 0, stream>>>(S, l, mpart, zpart);
  colreduce_comb<<<dim3(T_SEQ / 256, NB), 256, 0, stream>>>(mpart, zpart, mb, rzb);
  // P = exp(S-m)*rz (bf16), zero for masked rows
  pbuild<<<NB * T_SEQ, 256, 0, stream>>>(S, l, mb, rzb, Pb);
  // y[b] = x_b + P_b @ Vt_b^T   [2048,1024] bf16   (B = Vt cols b*2048.., ldb 8192)
  gemm_bt<2><<<dim3(1024 / 256, 2048 / 128, NB), 512, 0, stream>>>(
      Pb, Vt, yb, T_SEQ, T_SEQ, 8192, DIM, TT, 2048, TD, x, TD, 0.f);
  // out = relu(y @ Wo^T + bo)   f32
  gemm_bt<3><<<dim3(1024 / 256, 8192 / 128, 1), 512, 0, stream>>>(
      yb, wob, outp, DIM, DIM, DIM, DIM, 0, 0, 0, bo, 0, 0.f);
}

// Round 4
// 246.230 us; speedup vs baseline: 3.1295x; 1.0449x over previous
//
#include <hip/hip_runtime.h>
#include <hip/hip_fp16.h>

typedef unsigned short u16;
typedef __attribute__((ext_vector_type(8))) short bf16x8;
typedef __attribute__((ext_vector_type(4))) float f32x4;

#define T_SEQ 2048
#define DIM 1024
#define NB 4
#define NCH 16        // row chunks for column-softmax reduce
#define RCHUNK (T_SEQ / NCH)

__device__ __forceinline__ u16 f2bf(float f) {
  union { float f; unsigned u; } c; c.f = f;
  unsigned r = c.u + 0x7fffu + ((c.u >> 16) & 1u);
  return (u16)(r >> 16);
}

__device__ __forceinline__ void gload_lds16(const void* g, void* l) {
  __builtin_amdgcn_global_load_lds((const __attribute__((address_space(1))) void*)g,
                                   (__attribute__((address_space(3))) void*)l, 16, 0, 0);
}

#define SBAR() asm volatile("s_barrier" ::: "memory")
#define VMCNT0() asm volatile("s_waitcnt vmcnt(0)" ::: "memory")
#define VMCNT3() asm volatile("s_waitcnt vmcnt(3)" ::: "memory")
#define VMCNT4() asm volatile("s_waitcnt vmcnt(4)" ::: "memory")

// ---------------- LayerNorm: x (f32) -> x_norm (bf16) ----------------
__global__ __launch_bounds__(256) void ln_kernel(const float* __restrict__ x,
                                                 const float* __restrict__ gamma,
                                                 const float* __restrict__ beta,
                                                 u16* __restrict__ xn) {
  const int row = blockIdx.x;
  const int tid = threadIdx.x;
  const float4 v = *(const float4*)(x + (size_t)row * DIM + tid * 4);
  float s  = v.x + v.y + v.z + v.w;
  float ss = v.x * v.x + v.y * v.y + v.z * v.z + v.w * v.w;
#pragma unroll
  for (int o = 32; o > 0; o >>= 1) { s += __shfl_down(s, o); ss += __shfl_down(ss, o); }
  __shared__ float rs[4], rss[4];
  const int wid = tid >> 6, lane = tid & 63;
  if (lane == 0) { rs[wid] = s; rss[wid] = ss; }
  __syncthreads();
  s  = rs[0] + rs[1] + rs[2] + rs[3];
  ss = rss[0] + rss[1] + rss[2] + rss[3];
  const float mu = s * (1.f / DIM);
  const float var = ss * (1.f / DIM) - mu * mu;
  const float rstd = rsqrtf(var + 1e-5f);
  const float4 g  = *(const float4*)(gamma + tid * 4);
  const float4 be = *(const float4*)(beta + tid * 4);
  ushort4 o;
  o.x = f2bf((v.x - mu) * rstd * g.x + be.x);
  o.y = f2bf((v.y - mu) * rstd * g.y + be.y);
  o.z = f2bf((v.z - mu) * rstd * g.z + be.z);
  o.w = f2bf((v.w - mu) * rstd * g.w + be.w);
  *(ushort4*)(xn + (size_t)row * DIM + tid * 4) = o;
}

// ---------------- f32 -> bf16 weight convert, all 4 weights in one launch ---
__global__ __launch_bounds__(256) void wcvt4(const float* __restrict__ wq,
                                             const float* __restrict__ wk,
                                             const float* __restrict__ wv,
                                             const float* __restrict__ wo,
                                             u16* __restrict__ dqk,
                                             u16* __restrict__ dv,
                                             u16* __restrict__ dw) {
  const int sel = blockIdx.x >> 10;
  const size_t t = (size_t)(blockIdx.x & 1023) * 256 + threadIdx.x;
  const float* w = (sel == 0) ? wq : (sel == 1) ? wk : (sel == 2) ? wv : wo;
  u16* d = (sel == 0) ? dqk : (sel == 1) ? (dqk + 1048576) : (sel == 2) ? dv : dw;
  const float4 v = *(const float4*)(w + t * 4);
  ushort4 u; u.x = f2bf(v.x); u.y = f2bf(v.y); u.z = f2bf(v.z); u.w = f2bf(v.w);
  *(ushort4*)(d + t * 4) = u;
}

// ==== GEMM: C[M,N] = A[M,K]*B[N,K]^T.  BM x 256 tile, BK=32, ring-4 LDS, ===
// one s_barrier per phase, counted vmcnt, swizzled staging, setprio MFMA.
// BM=256: 2 phases/K-tile (acc 8x4).  BM=128: 1 phase/K-tile (acc 4x4).
// EPI 0: bf16   1: fp16*scale   2: bf16 + aux residual (batched f32)
// EPI 3: f32, +bias[col], relu
template <int EPI, int BM>
__global__ __launch_bounds__(512, 2) void gemm_bt(
    const u16* __restrict__ A, const u16* __restrict__ B, void* __restrict__ Cv,
    int K, int lda, int ldb, int ldc,
    long sA, long sB, long sC,
    const float* __restrict__ aux, long sAux, float scale) {
  constexpr int MI = BM / 32;                 // A frags per wave: 8 or 4
  __shared__ __align__(16) u16 As[4][BM * 32];
  __shared__ __align__(16) u16 Bs[4][256 * 32];
  const int bz = blockIdx.z;
  const u16* Ab = A + (size_t)bz * sA;
  const u16* Bb = B + (size_t)bz * sB;

  // XCD-aware bijective swizzle (nb % 8 == 0 for all our grids)
  const int nb = gridDim.x * gridDim.y;
  int bid = blockIdx.y * gridDim.x + blockIdx.x;
  bid = (bid & 7) * (nb >> 3) + (bid >> 3);
  const int gx = gridDim.x;
  const int tileN = (bid % gx) * 256;
  const int tileM = (bid / gx) * BM;

  const int t = threadIdx.x;
  const int lane = t & 63;
  const int wid = t >> 6;
  const int wm = wid >> 2, wn = wid & 3;      // 2 x 4 waves

  // ---- staging: thread t covers row (t>>2) [and +128], 16B slot (t&3).
  // LDS slot s of row r holds source k-chunk s ^ (r&3) ^ ((r>>2)&3).
  const int srow = t >> 2;
  const int qsw = (((t & 3) ^ (srow & 3) ^ ((srow >> 2) & 3))) * 8;
  const size_t aoff0 = (size_t)(tileM + srow) * lda + qsw;
  const size_t aoff1 = (size_t)(tileM + 128 + srow) * lda + qsw;   // BM=256 only
  const size_t boff0 = (size_t)(tileN + srow) * ldb + qsw;
  const size_t boff1 = (size_t)(tileN + 128 + srow) * ldb + qsw;

  // ---- fragment-read constants
  const int frow = lane & 15;
  const int kg = lane >> 4;
  const int ckk = ((kg ^ (lane & 3) ^ ((lane >> 2) & 3))) * 8;  // swizzled k-chunk

  f32x4 acc[MI][4] = {};
  const int NT = K >> 5;

  // ---- prologue: stage tiles 0,1 into slots 0,1
#pragma unroll
  for (int p = 0; p < 2; ++p) {
    const size_t kp = (size_t)p << 5;
    gload_lds16(Ab + aoff0 + kp, &As[p][t * 8]);
    gload_lds16(Bb + boff0 + kp, &Bs[p][t * 8]);
    if constexpr (BM == 256) gload_lds16(Ab + aoff1 + kp, &As[p][4096 + t * 8]);
    gload_lds16(Bb + boff1 + kp, &Bs[p][4096 + t * 8]);
  }
  if constexpr (BM == 256) VMCNT4(); else VMCNT3();   // tile 0 landed
  SBAR();

  for (int tau = 0; tau < NT; ++tau) {
    const int cur = tau & 3;
    const int nxt = (tau + 2) & 3;
    const bool st = (tau + 2 < NT);
    const size_t k0 = (size_t)(tau + 2) << 5;

    bf16x8 af[4], bf[4];
#pragma unroll
    for (int j = 0; j < 4; ++j)
      bf[j] = *(const bf16x8*)&Bs[cur][(wn * 64 + j * 16 + frow) * 32 + ckk];
#pragma unroll
    for (int i = 0; i < 4; ++i)
      af[i] = *(const bf16x8*)&As[cur][(wm * (BM / 2) + i * 16 + frow) * 32 + ckk];
    if (st) {
      gload_lds16(Ab + aoff0 + k0, &As[nxt][t * 8]);
      gload_lds16(Bb + boff0 + k0, &Bs[nxt][t * 8]);
      if constexpr (BM == 128) gload_lds16(Bb + boff1 + k0, &Bs[nxt][4096 + t * 8]);
    }
    if constexpr (BM == 128) { if (st) VMCNT3(); else VMCNT0(); }
    SBAR();
    __builtin_amdgcn_s_setprio(1);
#pragma unroll
    for (int i = 0; i < 4; ++i)
#pragma unroll
      for (int j = 0; j < 4; ++j)
        acc[i][j] = __builtin_amdgcn_mfma_f32_16x16x32_bf16(af[i], bf[j], acc[i][j], 0, 0, 0);
    __builtin_amdgcn_s_setprio(0);

    if constexpr (BM == 256) {
      bf16x8 af2[4];
#pragma unroll
      for (int i = 0; i < 4; ++i)
        af2[i] = *(const bf16x8*)&As[cur][(wm * 128 + (4 + i) * 16 + frow) * 32 + ckk];
      if (st) {
        gload_lds16(Ab + aoff1 + k0, &As[nxt][4096 + t * 8]);
        gload_lds16(Bb + boff1 + k0, &Bs[nxt][4096 + t * 8]);
      }
      if (st) VMCNT4(); else VMCNT0();
      SBAR();
      __builtin_amdgcn_s_setprio(1);
#pragma unroll
      for (int i = 0; i < 4; ++i)
#pragma unroll
        for (int j = 0; j < 4; ++j)
          acc[4 + i][j] = __builtin_amdgcn_mfma_f32_16x16x32_bf16(af2[i], bf[j], acc[4 + i][j], 0, 0, 0);
      __builtin_amdgcn_s_setprio(0);
    }
  }

  // ---------- epilogue ----------
  const int r0 = tileM + wm * (BM / 2) + (kg << 2);
  const int c0 = tileN + wn * 64 + frow;
#pragma unroll
  for (int i = 0; i < MI; ++i)
#pragma unroll
    for (int j = 0; j < 4; ++j)
#pragma unroll
      for (int r = 0; r < 4; ++r) {
        const int row = r0 + i * 16 + r, col = c0 + j * 16;
        const size_t idx = (size_t)row * ldc + col;
        float v = acc[i][j][r];
        if constexpr (EPI == 0) {
          ((u16*)Cv + (size_t)bz * sC)[idx] = f2bf(v);
        } else if constexpr (EPI == 1) {
          ((__half*)Cv + (size_t)bz * sC)[idx] = __float2half(v * scale);
        } else if constexpr (EPI == 2) {
          v += (aux + (size_t)bz * sAux)[idx];
          ((u16*)Cv + (size_t)bz * sC)[idx] = f2bf(v);
        } else {
          v += aux[col];
          ((float*)Cv + (size_t)bz * sC)[idx] = fmaxf(v, 0.f);
        }
      }
}

// ------- pass 1: per-column (axis=i) partial max & sumexp over a row chunk --
__global__ __launch_bounds__(256) void colreduce_part(const __half* __restrict__ S,
                                                      const int* __restrict__ l,
                                                      float* __restrict__ mp,
                                                      float* __restrict__ zp) {
  const int b = blockIdx.y;
  const int ch = blockIdx.z;
  const int j = blockIdx.x * 256 + threadIdx.x;
  const __half* Sb = S + (size_t)b * T_SEQ * T_SEQ;
  const int L = l[b];
  const int i0 = ch * RCHUNK;
  const int i1 = min(i0 + RCHUNK, L);

  float mm[4] = {-1e30f, -1e30f, -1e30f, -1e30f};
  float zz[4] = {0.f, 0.f, 0.f, 0.f};
  for (int i = i0; i < i1; i += 4) {
#pragma unroll
    for (int u = 0; u < 4; ++u) {
      const int ii = i + u;
      if (ii < i1) {
        const float s = __half2float(Sb[(size_t)ii * T_SEQ + j]);
        if (s > mm[u]) { zz[u] *= __expf(mm[u] - s); mm[u] = s; zz[u] += 1.f; }
        else           { zz[u] += __expf(s - mm[u]); }
      }
    }
  }
  float M = fmaxf(fmaxf(mm[0], mm[1]), fmaxf(mm[2], mm[3]));
  float Z = 0.f;
#pragma unroll
  for (int u = 0; u < 4; ++u) Z += zz[u] * __expf(mm[u] - M);

  const size_t o = ((size_t)ch * NB + b) * T_SEQ + j;
  mp[o] = M;
  zp[o] = Z;
}

// ------- pass 2: combine NCH partials per column -> m, 1/Z ------------------
__global__ __launch_bounds__(256) void colreduce_comb(const float* __restrict__ mp,
                                                      const float* __restrict__ zp,
                                                      float* __restrict__ m,
                                                      float* __restrict__ rz) {
  const int b = blockIdx.y;
  const int j = blockIdx.x * 256 + threadIdx.x;
  float M = -1e30f, Z = 0.f;
#pragma unroll
  for (int c = 0; c < NCH; ++c) {
    const size_t o = ((size_t)c * NB + b) * T_SEQ + j;
    const float mc = mp[o], zc = zp[o];
    const float nm = fmaxf(M, mc);
    Z = Z * __expf(M - nm) + zc * __expf(mc - nm);
    M = nm;
  }
  m[b * T_SEQ + j] = M;
  rz[b * T_SEQ + j] = 1.f / Z;
}

// ---------------- P = exp(S - m) / Z  (bf16, row-masked) -------------------
__global__ __launch_bounds__(256) void pbuild(const __half* __restrict__ S,
                                              const int* __restrict__ l,
                                              const float* __restrict__ m,
                                              const float* __restrict__ rz,
                                              u16* __restrict__ P) {
  const int b = blockIdx.x >> 11;
  const int i = blockIdx.x & (T_SEQ - 1);
  const int j0 = threadIdx.x * 8;
  const size_t off = ((size_t)blockIdx.x << 11) + j0;
  ushort4 o0, o1;
  if (i < l[b]) {
    const __half* sp = S + off;
    const float* mp = m + b * T_SEQ + j0;
    const float* zp = rz + b * T_SEQ + j0;
    u16 tmp[8];
#pragma unroll
    for (int t = 0; t < 8; ++t)
      tmp[t] = f2bf(__expf(__half2float(sp[t]) - mp[t]) * zp[t]);
    o0 = make_ushort4(tmp[0], tmp[1], tmp[2], tmp[3]);
    o1 = make_ushort4(tmp[4], tmp[5], tmp[6], tmp[7]);
  } else {
    o0 = make_ushort4(0, 0, 0, 0);
    o1 = make_ushort4(0, 0, 0, 0);
  }
  *(ushort4*)(P + off) = o0;
  *(ushort4*)(P + off + 4) = o1;
}

// ---------------------------------------------------------------------------
extern "C" void kernel_launch(void* const* d_in, const int* in_sizes, int n_in,
                              void* d_out, int out_size, void* d_ws, size_t ws_size,
                              hipStream_t stream) {
  (void)in_sizes; (void)n_in; (void)out_size; (void)ws_size;
  const float* x     = (const float*)d_in[0];
  const int*   l     = (const int*)d_in[1];
  const float* Wq    = (const float*)d_in[2];
  const float* Wk    = (const float*)d_in[3];
  const float* Wv    = (const float*)d_in[4];
  const float* Wo    = (const float*)d_in[5];
  const float* bo    = (const float*)d_in[6];
  const float* gamma = (const float*)d_in[7];
  const float* beta  = (const float*)d_in[8];

  char* ws = (char*)d_ws;
  const size_t MiB = 1024 * 1024;
  u16* xn   = (u16*)(ws);             // 16 MiB x_norm; later reused as y
  u16* wqkb = (u16*)(ws + 16 * MiB);  // 4 MiB: Wq rows then Wk rows (concat)
  u16* wvb  = (u16*)(ws + 20 * MiB);  // 2 MiB; later reused for softmax partials
  u16* wob  = (u16*)(ws + 22 * MiB);  // 2 MiB
  u16* QKb  = (u16*)(ws + 24 * MiB);  // 32 MiB: [8192][2048] Q|K; reused as P
  u16* Vt   = (u16*)(ws + 56 * MiB);  // 16 MiB: [1024][8192] V^T (all batches)
  float* mpart = (float*)(ws + 20 * MiB);                // 512 KiB (over dead wvb)
  float* zpart = (float*)(ws + 20 * MiB + 512 * 1024);   // 512 KiB
  float* mb  = (float*)(ws + 72 * MiB);
  float* rzb = (float*)(ws + 72 * MiB + 32 * 1024);
  u16* Pb = QKb;                      // P overwrites dead Q|K
  u16* yb = xn;
  __half* S = (__half*)d_out;         // d_out doubles as the 32 MiB score scratch
  float* outp = (float*)d_out;

  const long TD = (long)T_SEQ * DIM, TT = (long)T_SEQ * T_SEQ;
  const long TQK = (long)T_SEQ * 2048;

  ln_kernel<<<NB * T_SEQ, 256, 0, stream>>>(x, gamma, beta, xn);
  wcvt4<<<4096, 256, 0, stream>>>(Wq, Wk, Wv, Wo, wqkb, wvb, wob);

  // Q|K = xn @ [Wq;Wk]^T   [8192,2048]   grid 8x32 = 256
  gemm_bt<0, 256><<<dim3(8, 32, 1), 512, 0, stream>>>(
      xn, wqkb, QKb, DIM, DIM, DIM, 2048, 0, 0, 0, nullptr, 0, 0.f);
  // V^T = Wv_bf @ xn^T   [1024, 8192]    grid 32x8 = 256
  gemm_bt<0, 128><<<dim3(32, 8, 1), 512, 0, stream>>>(
      wvb, xn, Vt, DIM, DIM, DIM, 8192, 0, 0, 0, nullptr, 0, 0.f);
  // S[b] = (Q_b @ K_b^T) * scale -> fp16  grid 8x8x4 = 256
  gemm_bt<1, 256><<<dim3(8, 8, NB), 512, 0, stream>>>(
      QKb, QKb + 1024, S, DIM, 2048, 2048, T_SEQ, TQK, TQK, TT, nullptr, 0, 0.03125f);
  // column max / sumexp: chunked partials then combine
  colreduce_part<<<dim3(T_SEQ / 256, NB, NCH), 256, 0, stream>>>(S, l, mpart, zpart);
  colreduce_comb<<<dim3(T_SEQ / 256, NB), 256, 0, stream>>>(mpart, zpart, mb, rzb);
  // P = exp(S-m)*rz (bf16), zero for masked rows
  pbuild<<<NB * T_SEQ, 256, 0, stream>>>(S, l, mb, rzb, Pb);
  // y[b] = x_b + P_b @ Vt_b^T   [2048,1024] bf16   grid 4x16x4 = 256
  gemm_bt<2, 128><<<dim3(4, 16, NB), 512, 0, stream>>>(
      Pb, Vt, yb, T_SEQ, T_SEQ, 8192, DIM, TT, 2048, TD, x, TD, 0.f);
  // out = relu(y @ Wo^T + bo)   f32        grid 4x64 = 256
  gemm_bt<3, 128><<<dim3(4, 64, 1), 512, 0, stream>>>(
      yb, wob, outp, DIM, DIM, DIM, DIM, 0, 0, 0, bo, 0, 0.f);
}

// Round 5
// 209.962 us; speedup vs baseline: 3.6700x; 1.1727x over previous
//
#include <hip/hip_runtime.h>
#include <hip/hip_fp16.h>

typedef unsigned short u16;
typedef __attribute__((ext_vector_type(8))) short bf16x8;
typedef __attribute__((ext_vector_type(4))) float f32x4;

#define T_SEQ 2048
#define DIM 1024
#define NB 4
#define NCH 8         // row chunks for column-softmax reduce (= S-GEMM tileM count)

__device__ __forceinline__ u16 f2bf(float f) {
  union { float f; unsigned u; } c; c.f = f;
  unsigned r = c.u + 0x7fffu + ((c.u >> 16) & 1u);
  return (u16)(r >> 16);
}

__device__ __forceinline__ void gload_lds16(const void* g, void* l) {
  __builtin_amdgcn_global_load_lds((const __attribute__((address_space(1))) void*)g,
                                   (__attribute__((address_space(3))) void*)l, 16, 0, 0);
}

#define SBAR() asm volatile("s_barrier" ::: "memory")
// pre-barrier wait: retire prefetch stage tau+1 (vmcnt) AND this wave's
// ds_reads (lgkmcnt) so the barrier globally licenses slot reuse (ring-4,
// depth-3: slot overwritten one barrier after its reads issue).
#define WVL(n) asm volatile("s_waitcnt vmcnt(" n ") lgkmcnt(0)" ::: "memory")

// ---------------- LayerNorm: x (f32) -> x_norm (bf16) ----------------
__global__ __launch_bounds__(256) void ln_kernel(const float* __restrict__ x,
                                                 const float* __restrict__ gamma,
                                                 const float* __restrict__ beta,
                                                 u16* __restrict__ xn) {
  const int row = blockIdx.x;
  const int tid = threadIdx.x;
  const float4 v = *(const float4*)(x + (size_t)row * DIM + tid * 4);
  float s  = v.x + v.y + v.z + v.w;
  float ss = v.x * v.x + v.y * v.y + v.z * v.z + v.w * v.w;
#pragma unroll
  for (int o = 32; o > 0; o >>= 1) { s += __shfl_down(s, o); ss += __shfl_down(ss, o); }
  __shared__ float rs[4], rss[4];
  const int wid = tid >> 6, lane = tid & 63;
  if (lane == 0) { rs[wid] = s; rss[wid] = ss; }
  __syncthreads();
  s  = rs[0] + rs[1] + rs[2] + rs[3];
  ss = rss[0] + rss[1] + rss[2] + rss[3];
  const float mu = s * (1.f / DIM);
  const float var = ss * (1.f / DIM) - mu * mu;
  const float rstd = rsqrtf(var + 1e-5f);
  const float4 g  = *(const float4*)(gamma + tid * 4);
  const float4 be = *(const float4*)(beta + tid * 4);
  ushort4 o;
  o.x = f2bf((v.x - mu) * rstd * g.x + be.x);
  o.y = f2bf((v.y - mu) * rstd * g.y + be.y);
  o.z = f2bf((v.z - mu) * rstd * g.z + be.z);
  o.w = f2bf((v.w - mu) * rstd * g.w + be.w);
  *(ushort4*)(xn + (size_t)row * DIM + tid * 4) = o;
}

// ---------------- f32 -> bf16 weight convert, all 4 weights in one launch ---
__global__ __launch_bounds__(256) void wcvt4(const float* __restrict__ wq,
                                             const float* __restrict__ wk,
                                             const float* __restrict__ wv,
                                             const float* __restrict__ wo,
                                             u16* __restrict__ dqk,
                                             u16* __restrict__ dv,
                                             u16* __restrict__ dw) {
  const int sel = blockIdx.x >> 10;
  const size_t t = (size_t)(blockIdx.x & 1023) * 256 + threadIdx.x;
  const float* w = (sel == 0) ? wq : (sel == 1) ? wk : (sel == 2) ? wv : wo;
  u16* d = (sel == 0) ? dqk : (sel == 1) ? (dqk + 1048576) : (sel == 2) ? dv : dw;
  const float4 v = *(const float4*)(w + t * 4);
  ushort4 u; u.x = f2bf(v.x); u.y = f2bf(v.y); u.z = f2bf(v.z); u.w = f2bf(v.w);
  *(ushort4*)(d + t * 4) = u;
}

// ==== GEMM: C[M,N] = A[M,K]*B[N,K]^T.  BM x 256 tile, BK=32, ring-4 LDS, ===
// depth-3 prefetch with counted vmcnt, one barrier per phase, swizzled
// staging, setprio MFMA.
// BM=256: 2 phases/K-tile (acc 8x4).  BM=128: 1 phase/K-tile (acc 4x4).
// EPI 0: bf16   1: fp16*scale + fused per-column masked (max,sumexp) partials
// EPI 2: bf16 + aux residual (batched f32)   3: f32, +bias[col], relu
template <int EPI, int BM>
__global__ __launch_bounds__(512, 2) void gemm_bt(
    const u16* __restrict__ A, const u16* __restrict__ B, void* __restrict__ Cv,
    int K, int lda, int ldb, int ldc,
    long sA, long sB, long sC,
    const float* __restrict__ aux, long sAux, float scale,
    const int* __restrict__ lptr, float* __restrict__ mpQ, float* __restrict__ zpQ) {
  constexpr int MI = BM / 32;                 // A frags per wave: 8 or 4
  __shared__ __align__(16) u16 As[4][BM * 32];
  __shared__ __align__(16) u16 Bs[4][256 * 32];
  const int bz = blockIdx.z;
  const u16* Ab = A + (size_t)bz * sA;
  const u16* Bb = B + (size_t)bz * sB;

  // XCD-aware bijective swizzle (nb % 8 == 0 for all our grids)
  const int nb = gridDim.x * gridDim.y;
  int bid = blockIdx.y * gridDim.x + blockIdx.x;
  bid = (bid & 7) * (nb >> 3) + (bid >> 3);
  const int gx = gridDim.x;
  const int tileN = (bid % gx) * 256;
  const int tileM = (bid / gx) * BM;

  const int t = threadIdx.x;
  const int lane = t & 63;
  const int wid = t >> 6;
  const int wm = wid >> 2, wn = wid & 3;      // 2 x 4 waves

  // ---- staging: thread t covers row (t>>2) [and +128], 16B slot (t&3).
  // LDS slot s of row r holds source k-chunk s ^ (r&3) ^ ((r>>2)&3).
  const int srow = t >> 2;
  const int qsw = (((t & 3) ^ (srow & 3) ^ ((srow >> 2) & 3))) * 8;
  const size_t aoff0 = (size_t)(tileM + srow) * lda + qsw;
  const size_t aoff1 = (size_t)(tileM + 128 + srow) * lda + qsw;   // BM=256 only
  const size_t boff0 = (size_t)(tileN + srow) * ldb + qsw;
  const size_t boff1 = (size_t)(tileN + 128 + srow) * ldb + qsw;

  // ---- fragment-read constants
  const int frow = lane & 15;
  const int kg = lane >> 4;
  const int ckk = ((kg ^ (lane & 3) ^ ((lane >> 2) & 3))) * 8;  // swizzled k-chunk

  f32x4 acc[MI][4] = {};
  const int NT = K >> 5;

  // ---- prologue: stage tiles 0,1,2 into slots 0,1,2 (depth 3)
#pragma unroll
  for (int p = 0; p < 3; ++p) {
    const size_t kp = (size_t)p << 5;
    gload_lds16(Ab + aoff0 + kp, &As[p][t * 8]);
    gload_lds16(Bb + boff0 + kp, &Bs[p][t * 8]);
    if constexpr (BM == 256) gload_lds16(Ab + aoff1 + kp, &As[p][4096 + t * 8]);
    gload_lds16(Bb + boff1 + kp, &Bs[p][4096 + t * 8]);
  }
  if constexpr (BM == 256) { asm volatile("s_waitcnt vmcnt(8)" ::: "memory"); }
  else                     { asm volatile("s_waitcnt vmcnt(6)" ::: "memory"); }
  SBAR();

  for (int tau = 0; tau < NT; ++tau) {
    const int cur = tau & 3;
    const int tgt = (tau + 3) & 3;
    const bool st = (tau + 3 < NT);
    const size_t k0 = (size_t)(tau + 3) << 5;

    bf16x8 af[4], bf[4];
#pragma unroll
    for (int j = 0; j < 4; ++j)
      bf[j] = *(const bf16x8*)&Bs[cur][(wn * 64 + j * 16 + frow) * 32 + ckk];
#pragma unroll
    for (int i = 0; i < 4; ++i)
      af[i] = *(const bf16x8*)&As[cur][(wm * (BM / 2) + i * 16 + frow) * 32 + ckk];
    if (st) {
      gload_lds16(Ab + aoff0 + k0, &As[tgt][t * 8]);
      gload_lds16(Bb + boff0 + k0, &Bs[tgt][t * 8]);
      if constexpr (BM == 128) gload_lds16(Bb + boff1 + k0, &Bs[tgt][4096 + t * 8]);
    }
    if constexpr (BM == 128) {
      // retire stage tau+1; stages tau+2, tau+3 (3 loads each) stay in flight
      if (tau < NT - 3) WVL("6"); else if (tau == NT - 3) WVL("3"); else WVL("0");
    }
    SBAR();
    __builtin_amdgcn_s_setprio(1);
#pragma unroll
    for (int i = 0; i < 4; ++i)
#pragma unroll
      for (int j = 0; j < 4; ++j)
        acc[i][j] = __builtin_amdgcn_mfma_f32_16x16x32_bf16(af[i], bf[j], acc[i][j], 0, 0, 0);
    __builtin_amdgcn_s_setprio(0);

    if constexpr (BM == 256) {
      bf16x8 af2[4];
#pragma unroll
      for (int i = 0; i < 4; ++i)
        af2[i] = *(const bf16x8*)&As[cur][(wm * 128 + (4 + i) * 16 + frow) * 32 + ckk];
      if (st) {
        gload_lds16(Ab + aoff1 + k0, &As[tgt][4096 + t * 8]);
        gload_lds16(Bb + boff1 + k0, &Bs[tgt][4096 + t * 8]);
      }
      // retire stage tau+1; stages tau+2, tau+3 (4 loads each) stay in flight
      if (tau < NT - 3) WVL("8"); else if (tau == NT - 3) WVL("4"); else WVL("0");
      SBAR();
      __builtin_amdgcn_s_setprio(1);
#pragma unroll
      for (int i = 0; i < 4; ++i)
#pragma unroll
        for (int j = 0; j < 4; ++j)
          acc[4 + i][j] = __builtin_amdgcn_mfma_f32_16x16x32_bf16(af2[i], bf[j], acc[4 + i][j], 0, 0, 0);
      __builtin_amdgcn_s_setprio(0);
    }
  }

  // ---------- epilogue ----------
  const int r0 = tileM + wm * (BM / 2) + (kg << 2);
  const int c0 = tileN + wn * 64 + frow;
#pragma unroll
  for (int i = 0; i < MI; ++i)
#pragma unroll
    for (int j = 0; j < 4; ++j)
#pragma unroll
      for (int r = 0; r < 4; ++r) {
        const int row = r0 + i * 16 + r, col = c0 + j * 16;
        const size_t idx = (size_t)row * ldc + col;
        float v = acc[i][j][r];
        if constexpr (EPI == 0) {
          ((u16*)Cv + (size_t)bz * sC)[idx] = f2bf(v);
        } else if constexpr (EPI == 1) {
          ((__half*)Cv + (size_t)bz * sC)[idx] = __float2half(v * scale);
        } else if constexpr (EPI == 2) {
          v += (aux + (size_t)bz * sAux)[idx];
          ((u16*)Cv + (size_t)bz * sC)[idx] = f2bf(v);
        } else {
          v += aux[col];
          ((float*)Cv + (size_t)bz * sC)[idx] = fmaxf(v, 0.f);
        }
      }

  // ---- EPI 1: fused per-column (over rows i, masked i<L) max & sumexp ------
  if constexpr (EPI == 1) {
    const int L = lptr[bz];
    __shared__ float2 red[2][4][4][16];   // [wm][wn][j][frow]
    float Ms[4], Zs[4];
#pragma unroll
    for (int j = 0; j < 4; ++j) {
      float mj = -3e38f;
#pragma unroll
      for (int i = 0; i < MI; ++i)
#pragma unroll
        for (int r = 0; r < 4; ++r) {
          const int row = r0 + i * 16 + r;
          if (row < L) mj = fmaxf(mj, acc[i][j][r] * scale);
        }
      mj = fmaxf(mj, __shfl_xor(mj, 16, 64));
      mj = fmaxf(mj, __shfl_xor(mj, 32, 64));
      float zj = 0.f;
#pragma unroll
      for (int i = 0; i < MI; ++i)
#pragma unroll
        for (int r = 0; r < 4; ++r) {
          const int row = r0 + i * 16 + r;
          if (row < L) zj += __expf(acc[i][j][r] * scale - mj);
        }
      zj += __shfl_xor(zj, 16, 64);
      zj += __shfl_xor(zj, 32, 64);
      Ms[j] = mj; Zs[j] = zj;
    }
    if (lane < 16) {
#pragma unroll
      for (int j = 0; j < 4; ++j) red[wm][wn][j][frow] = make_float2(Ms[j], Zs[j]);
    }
    __syncthreads();
    if (wm == 0 && lane < 16) {
#pragma unroll
      for (int j = 0; j < 4; ++j) {
        const float2 a = red[0][wn][j][frow];
        const float2 b = red[1][wn][j][frow];
        const float M = fmaxf(a.x, b.x);
        const float Z = a.y * __expf(a.x - M) + b.y * __expf(b.x - M);
        const int col = tileN + wn * 64 + j * 16 + frow;
        const size_t o = ((size_t)(tileM >> 8) * NB + bz) * T_SEQ + col;
        mpQ[o] = M; zpQ[o] = Z;
      }
    }
  }
}

// ------- combine NCH chunk partials per column -> m, 1/Z --------------------
__global__ __launch_bounds__(256) void colreduce_comb(const float* __restrict__ mp,
                                                      const float* __restrict__ zp,
                                                      float* __restrict__ m,
                                                      float* __restrict__ rz) {
  const int b = blockIdx.y;
  const int j = blockIdx.x * 256 + threadIdx.x;
  float M = -3e38f, Z = 0.f;
#pragma unroll
  for (int c = 0; c < NCH; ++c) {
    const size_t o = ((size_t)c * NB + b) * T_SEQ + j;
    const float mc = mp[o], zc = zp[o];
    const float nm = fmaxf(M, mc);
    Z = Z * __expf(M - nm) + zc * __expf(mc - nm);
    M = nm;
  }
  m[b * T_SEQ + j] = M;
  rz[b * T_SEQ + j] = 1.f / Z;
}

// ---------------- P = exp(S - m) / Z  (bf16, row-masked) -------------------
__global__ __launch_bounds__(256) void pbuild(const __half* __restrict__ S,
                                              const int* __restrict__ l,
                                              const float* __restrict__ m,
                                              const float* __restrict__ rz,
                                              u16* __restrict__ P) {
  const int b = blockIdx.x >> 11;
  const int i = blockIdx.x & (T_SEQ - 1);
  const int j0 = threadIdx.x * 8;
  const size_t off = ((size_t)blockIdx.x << 11) + j0;
  ushort4 o0, o1;
  if (i < l[b]) {
    const __half* sp = S + off;
    const float* mp = m + b * T_SEQ + j0;
    const float* zp = rz + b * T_SEQ + j0;
    u16 tmp[8];
#pragma unroll
    for (int t = 0; t < 8; ++t)
      tmp[t] = f2bf(__expf(__half2float(sp[t]) - mp[t]) * zp[t]);
    o0 = make_ushort4(tmp[0], tmp[1], tmp[2], tmp[3]);
    o1 = make_ushort4(tmp[4], tmp[5], tmp[6], tmp[7]);
  } else {
    o0 = make_ushort4(0, 0, 0, 0);
    o1 = make_ushort4(0, 0, 0, 0);
  }
  *(ushort4*)(P + off) = o0;
  *(ushort4*)(P + off + 4) = o1;
}

// ---------------------------------------------------------------------------
extern "C" void kernel_launch(void* const* d_in, const int* in_sizes, int n_in,
                              void* d_out, int out_size, void* d_ws, size_t ws_size,
                              hipStream_t stream) {
  (void)in_sizes; (void)n_in; (void)out_size; (void)ws_size;
  const float* x     = (const float*)d_in[0];
  const int*   l     = (const int*)d_in[1];
  const float* Wq    = (const float*)d_in[2];
  const float* Wk    = (const float*)d_in[3];
  const float* Wv    = (const float*)d_in[4];
  const float* Wo    = (const float*)d_in[5];
  const float* bo    = (const float*)d_in[6];
  const float* gamma = (const float*)d_in[7];
  const float* beta  = (const float*)d_in[8];

  char* ws = (char*)d_ws;
  const size_t MiB = 1024 * 1024;
  u16* xn   = (u16*)(ws);             // 16 MiB x_norm; later reused as y
  u16* wqkb = (u16*)(ws + 16 * MiB);  // 4 MiB: Wq rows then Wk rows (concat)
  u16* wvb  = (u16*)(ws + 20 * MiB);  // 2 MiB; later reused for softmax partials
  u16* wob  = (u16*)(ws + 22 * MiB);  // 2 MiB
  u16* QKb  = (u16*)(ws + 24 * MiB);  // 32 MiB: [8192][2048] Q|K; reused as P
  u16* Vt   = (u16*)(ws + 56 * MiB);  // 16 MiB: [1024][8192] V^T (all batches)
  float* mpart = (float*)(ws + 20 * MiB);                // 256 KiB (over dead wvb)
  float* zpart = (float*)(ws + 20 * MiB + 512 * 1024);   // 256 KiB
  float* mb  = (float*)(ws + 72 * MiB);
  float* rzb = (float*)(ws + 72 * MiB + 32 * 1024);
  u16* Pb = QKb;                      // P overwrites dead Q|K
  u16* yb = xn;
  __half* S = (__half*)d_out;         // d_out doubles as the 32 MiB score scratch
  float* outp = (float*)d_out;

  const long TD = (long)T_SEQ * DIM, TT = (long)T_SEQ * T_SEQ;
  const long TQK = (long)T_SEQ * 2048;

  ln_kernel<<<NB * T_SEQ, 256, 0, stream>>>(x, gamma, beta, xn);
  wcvt4<<<4096, 256, 0, stream>>>(Wq, Wk, Wv, Wo, wqkb, wvb, wob);

  // Q|K = xn @ [Wq;Wk]^T   [8192,2048]   grid 8x32 = 256
  gemm_bt<0, 256><<<dim3(8, 32, 1), 512, 0, stream>>>(
      xn, wqkb, QKb, DIM, DIM, DIM, 2048, 0, 0, 0, nullptr, 0, 0.f,
      nullptr, nullptr, nullptr);
  // V^T = Wv_bf @ xn^T   [1024, 8192]    grid 32x8 = 256
  gemm_bt<0, 128><<<dim3(32, 8, 1), 512, 0, stream>>>(
      wvb, xn, Vt, DIM, DIM, DIM, 8192, 0, 0, 0, nullptr, 0, 0.f,
      nullptr, nullptr, nullptr);
  // S[b] = (Q_b @ K_b^T)*scale -> fp16, + fused per-column partial (m,z)
  gemm_bt<1, 256><<<dim3(8, 8, NB), 512, 0, stream>>>(
      QKb, QKb + 1024, S, DIM, 2048, 2048, T_SEQ, TQK, TQK, TT, nullptr, 0, 0.03125f,
      l, mpart, zpart);
  // combine 8 chunk partials -> m, 1/Z
  colreduce_comb<<<dim3(T_SEQ / 256, NB), 256, 0, stream>>>(mpart, zpart, mb, rzb);
  // P = exp(S-m)*rz (bf16), zero for masked rows
  pbuild<<<NB * T_SEQ, 256, 0, stream>>>(S, l, mb, rzb, Pb);
  // y[b] = x_b + P_b @ Vt_b^T   [2048,1024] bf16   grid 4x16x4 = 256
  gemm_bt<2, 128><<<dim3(4, 16, NB), 512, 0, stream>>>(
      Pb, Vt, yb, T_SEQ, T_SEQ, 8192, DIM, TT, 2048, TD, x, TD, 0.f,
      nullptr, nullptr, nullptr);
  // out = relu(y @ Wo^T + bo)   f32        grid 4x64 = 256
  gemm_bt<3, 128><<<dim3(4, 64, 1), 512, 0, stream>>>(
      yb, wob, outp, DIM, DIM, DIM, DIM, 0, 0, 0, bo, 0, 0.f,
      nullptr, nullptr, nullptr);
}

// Round 6
// 208.386 us; speedup vs baseline: 3.6978x; 1.0076x over previous
//
#include <hip/hip_runtime.h>
#include <hip/hip_fp16.h>

typedef unsigned short u16;
typedef __attribute__((ext_vector_type(8))) short bf16x8;
typedef __attribute__((ext_vector_type(4))) float f32x4;

#define T_SEQ 2048
#define DIM 1024
#define NB 4
#define NCH 8         // row chunks for column-softmax reduce (= S-GEMM tileM count)

__device__ __forceinline__ u16 f2bf(float f) {
  union { float f; unsigned u; } c; c.f = f;
  unsigned r = c.u + 0x7fffu + ((c.u >> 16) & 1u);
  return (u16)(r >> 16);
}

__device__ __forceinline__ void gload_lds16(const void* g, void* l) {
  __builtin_amdgcn_global_load_lds((const __attribute__((address_space(1))) void*)g,
                                   (__attribute__((address_space(3))) void*)l, 16, 0, 0);
}

#define SBAR() asm volatile("s_barrier" ::: "memory")
// pre-barrier wait: retire prefetch stage tau+1 (vmcnt) AND this wave's
// ds_reads (lgkmcnt) so the barrier globally licenses slot reuse (ring-4,
// depth-3: slot overwritten one barrier after its reads issue).
#define WVL(n) asm volatile("s_waitcnt vmcnt(" n ") lgkmcnt(0)" ::: "memory")

// ---------------- LayerNorm: x (f32) -> x_norm (bf16) ----------------
__global__ __launch_bounds__(256) void ln_kernel(const float* __restrict__ x,
                                                 const float* __restrict__ gamma,
                                                 const float* __restrict__ beta,
                                                 u16* __restrict__ xn) {
  const int row = blockIdx.x;
  const int tid = threadIdx.x;
  const float4 v = *(const float4*)(x + (size_t)row * DIM + tid * 4);
  float s  = v.x + v.y + v.z + v.w;
  float ss = v.x * v.x + v.y * v.y + v.z * v.z + v.w * v.w;
#pragma unroll
  for (int o = 32; o > 0; o >>= 1) { s += __shfl_down(s, o); ss += __shfl_down(ss, o); }
  __shared__ float rs[4], rss[4];
  const int wid = tid >> 6, lane = tid & 63;
  if (lane == 0) { rs[wid] = s; rss[wid] = ss; }
  __syncthreads();
  s  = rs[0] + rs[1] + rs[2] + rs[3];
  ss = rss[0] + rss[1] + rss[2] + rss[3];
  const float mu = s * (1.f / DIM);
  const float var = ss * (1.f / DIM) - mu * mu;
  const float rstd = rsqrtf(var + 1e-5f);
  const float4 g  = *(const float4*)(gamma + tid * 4);
  const float4 be = *(const float4*)(beta + tid * 4);
  ushort4 o;
  o.x = f2bf((v.x - mu) * rstd * g.x + be.x);
  o.y = f2bf((v.y - mu) * rstd * g.y + be.y);
  o.z = f2bf((v.z - mu) * rstd * g.z + be.z);
  o.w = f2bf((v.w - mu) * rstd * g.w + be.w);
  *(ushort4*)(xn + (size_t)row * DIM + tid * 4) = o;
}

// ---------------- f32 -> bf16 weight convert, all 4 weights in one launch ---
__global__ __launch_bounds__(256) void wcvt4(const float* __restrict__ wq,
                                             const float* __restrict__ wk,
                                             const float* __restrict__ wv,
                                             const float* __restrict__ wo,
                                             u16* __restrict__ dqk,
                                             u16* __restrict__ dv,
                                             u16* __restrict__ dw) {
  const int sel = blockIdx.x >> 10;
  const size_t t = (size_t)(blockIdx.x & 1023) * 256 + threadIdx.x;
  const float* w = (sel == 0) ? wq : (sel == 1) ? wk : (sel == 2) ? wv : wo;
  u16* d = (sel == 0) ? dqk : (sel == 1) ? (dqk + 1048576) : (sel == 2) ? dv : dw;
  const float4 v = *(const float4*)(w + t * 4);
  ushort4 u; u.x = f2bf(v.x); u.y = f2bf(v.y); u.z = f2bf(v.z); u.w = f2bf(v.w);
  *(ushort4*)(d + t * 4) = u;
}

// ==== GEMM: C[M,N] = A[M,K]*B[N,K]^T.  BM x 256 tile, BK=32, ring-4 LDS, ===
// depth-3 prefetch with counted vmcnt, one barrier per phase, swizzled
// staging, setprio MFMA.
// BM=256: 2 phases/K-tile (acc 8x4).  BM=128: 1 phase/K-tile (acc 4x4).
// EPI 0: bf16   1: fp16*scale + fused per-column masked (max,sumexp) partials
// EPI 2: bf16 + aux residual (batched f32)   3: f32, +bias[col], relu
// MSK 0: none
// MSK 1 (S):  skip tile entirely if tileM >= l[bz]          (rows dead)
// MSK 2 (PV): if tileM >= l[bz], emit y = bf16(x) and skip  (P rows zero)
// MSK 3 (QK): skip Q-half tiles whose rows are all >= l[batch]
template <int EPI, int BM, int MSK>
__global__ __launch_bounds__(512, 2) void gemm_bt(
    const u16* __restrict__ A, const u16* __restrict__ B, void* __restrict__ Cv,
    int K, int lda, int ldb, int ldc,
    long sA, long sB, long sC,
    const float* __restrict__ aux, long sAux, float scale,
    const int* __restrict__ lptr, float* __restrict__ mpQ, float* __restrict__ zpQ) {
  constexpr int MI = BM / 32;                 // A frags per wave: 8 or 4
  __shared__ __align__(16) u16 As[4][BM * 32];
  __shared__ __align__(16) u16 Bs[4][256 * 32];
  const int bz = blockIdx.z;
  const u16* Ab = A + (size_t)bz * sA;
  const u16* Bb = B + (size_t)bz * sB;

  // XCD-aware bijective swizzle (nb % 8 == 0 for all our grids)
  const int nb = gridDim.x * gridDim.y;
  int bid = blockIdx.y * gridDim.x + blockIdx.x;
  bid = (bid & 7) * (nb >> 3) + (bid >> 3);
  const int gx = gridDim.x;
  const int tileN = (bid % gx) * 256;
  const int tileM = (bid / gx) * BM;

  const int t = threadIdx.x;

  // ---- runtime dead-tile skipping from the row mask --------------------
  if constexpr (MSK == 1) {
    if (tileM >= lptr[bz]) return;            // S rows >= L are never read
  }
  if constexpr (MSK == 3) {
    // Q-half tile with all rows masked: its values are never consumed
    if (((tileM & (T_SEQ - 1)) >= lptr[tileM >> 11]) && tileN < DIM) return;
  }
  if constexpr (MSK == 2) {
    if (tileM >= lptr[bz]) {                  // P rows zero -> y = x
      const float* xb = aux + (size_t)bz * sAux;
      u16* yo = (u16*)Cv + (size_t)bz * sC;
      for (int e = t; e < (BM * 256) / 8; e += 512) {
        const int row = tileM + (e >> 5);
        const int col = tileN + ((e & 31) << 3);
        const float4 v0 = *(const float4*)(xb + (size_t)row * ldc + col);
        const float4 v1 = *(const float4*)(xb + (size_t)row * ldc + col + 4);
        ushort4 o0; o0.x = f2bf(v0.x); o0.y = f2bf(v0.y); o0.z = f2bf(v0.z); o0.w = f2bf(v0.w);
        ushort4 o1; o1.x = f2bf(v1.x); o1.y = f2bf(v1.y); o1.z = f2bf(v1.z); o1.w = f2bf(v1.w);
        *(ushort4*)(yo + (size_t)row * ldc + col) = o0;
        *(ushort4*)(yo + (size_t)row * ldc + col + 4) = o1;
      }
      return;
    }
  }

  const int lane = t & 63;
  const int wid = t >> 6;
  const int wm = wid >> 2, wn = wid & 3;      // 2 x 4 waves

  // ---- staging: thread t covers row (t>>2) [and +128], 16B slot (t&3).
  // LDS slot s of row r holds source k-chunk s ^ (r&3) ^ ((r>>2)&3).
  const int srow = t >> 2;
  const int qsw = (((t & 3) ^ (srow & 3) ^ ((srow >> 2) & 3))) * 8;
  const size_t aoff0 = (size_t)(tileM + srow) * lda + qsw;
  const size_t aoff1 = (size_t)(tileM + 128 + srow) * lda + qsw;   // BM=256 only
  const size_t boff0 = (size_t)(tileN + srow) * ldb + qsw;
  const size_t boff1 = (size_t)(tileN + 128 + srow) * ldb + qsw;

  // ---- fragment-read constants
  const int frow = lane & 15;
  const int kg = lane >> 4;
  const int ckk = ((kg ^ (lane & 3) ^ ((lane >> 2) & 3))) * 8;  // swizzled k-chunk

  f32x4 acc[MI][4] = {};
  const int NT = K >> 5;

  // ---- prologue: stage tiles 0,1,2 into slots 0,1,2 (depth 3)
#pragma unroll
  for (int p = 0; p < 3; ++p) {
    const size_t kp = (size_t)p << 5;
    gload_lds16(Ab + aoff0 + kp, &As[p][t * 8]);
    gload_lds16(Bb + boff0 + kp, &Bs[p][t * 8]);
    if constexpr (BM == 256) gload_lds16(Ab + aoff1 + kp, &As[p][4096 + t * 8]);
    gload_lds16(Bb + boff1 + kp, &Bs[p][4096 + t * 8]);
  }
  if constexpr (BM == 256) { asm volatile("s_waitcnt vmcnt(8)" ::: "memory"); }
  else                     { asm volatile("s_waitcnt vmcnt(6)" ::: "memory"); }
  SBAR();

  for (int tau = 0; tau < NT; ++tau) {
    const int cur = tau & 3;
    const int tgt = (tau + 3) & 3;
    const bool st = (tau + 3 < NT);
    const size_t k0 = (size_t)(tau + 3) << 5;

    bf16x8 af[4], bf[4];
#pragma unroll
    for (int j = 0; j < 4; ++j)
      bf[j] = *(const bf16x8*)&Bs[cur][(wn * 64 + j * 16 + frow) * 32 + ckk];
#pragma unroll
    for (int i = 0; i < 4; ++i)
      af[i] = *(const bf16x8*)&As[cur][(wm * (BM / 2) + i * 16 + frow) * 32 + ckk];
    if (st) {
      gload_lds16(Ab + aoff0 + k0, &As[tgt][t * 8]);
      gload_lds16(Bb + boff0 + k0, &Bs[tgt][t * 8]);
      if constexpr (BM == 128) gload_lds16(Bb + boff1 + k0, &Bs[tgt][4096 + t * 8]);
    }
    if constexpr (BM == 128) {
      // retire stage tau+1; stages tau+2, tau+3 (3 loads each) stay in flight
      if (tau < NT - 3) WVL("6"); else if (tau == NT - 3) WVL("3"); else WVL("0");
    }
    SBAR();
    __builtin_amdgcn_s_setprio(1);
#pragma unroll
    for (int i = 0; i < 4; ++i)
#pragma unroll
      for (int j = 0; j < 4; ++j)
        acc[i][j] = __builtin_amdgcn_mfma_f32_16x16x32_bf16(af[i], bf[j], acc[i][j], 0, 0, 0);
    __builtin_amdgcn_s_setprio(0);

    if constexpr (BM == 256) {
      bf16x8 af2[4];
#pragma unroll
      for (int i = 0; i < 4; ++i)
        af2[i] = *(const bf16x8*)&As[cur][(wm * 128 + (4 + i) * 16 + frow) * 32 + ckk];
      if (st) {
        gload_lds16(Ab + aoff1 + k0, &As[tgt][4096 + t * 8]);
        gload_lds16(Bb + boff1 + k0, &Bs[tgt][4096 + t * 8]);
      }
      // retire stage tau+1; stages tau+2, tau+3 (4 loads each) stay in flight
      if (tau < NT - 3) WVL("8"); else if (tau == NT - 3) WVL("4"); else WVL("0");
      SBAR();
      __builtin_amdgcn_s_setprio(1);
#pragma unroll
      for (int i = 0; i < 4; ++i)
#pragma unroll
        for (int j = 0; j < 4; ++j)
          acc[4 + i][j] = __builtin_amdgcn_mfma_f32_16x16x32_bf16(af2[i], bf[j], acc[4 + i][j], 0, 0, 0);
      __builtin_amdgcn_s_setprio(0);
    }
  }

  // ---------- epilogue ----------
  const int r0 = tileM + wm * (BM / 2) + (kg << 2);
  const int c0 = tileN + wn * 64 + frow;
#pragma unroll
  for (int i = 0; i < MI; ++i)
#pragma unroll
    for (int j = 0; j < 4; ++j)
#pragma unroll
      for (int r = 0; r < 4; ++r) {
        const int row = r0 + i * 16 + r, col = c0 + j * 16;
        const size_t idx = (size_t)row * ldc + col;
        float v = acc[i][j][r];
        if constexpr (EPI == 0) {
          ((u16*)Cv + (size_t)bz * sC)[idx] = f2bf(v);
        } else if constexpr (EPI == 1) {
          ((__half*)Cv + (size_t)bz * sC)[idx] = __float2half(v * scale);
        } else if constexpr (EPI == 2) {
          v += (aux + (size_t)bz * sAux)[idx];
          ((u16*)Cv + (size_t)bz * sC)[idx] = f2bf(v);
        } else {
          v += aux[col];
          ((float*)Cv + (size_t)bz * sC)[idx] = fmaxf(v, 0.f);
        }
      }

  // ---- EPI 1: fused per-column (over rows i, masked i<L) max & sumexp ------
  if constexpr (EPI == 1) {
    const int L = lptr[bz];
    __shared__ float2 red[2][4][4][16];   // [wm][wn][j][frow]
    float Ms[4], Zs[4];
#pragma unroll
    for (int j = 0; j < 4; ++j) {
      float mj = -3e38f;
#pragma unroll
      for (int i = 0; i < MI; ++i)
#pragma unroll
        for (int r = 0; r < 4; ++r) {
          const int row = r0 + i * 16 + r;
          if (row < L) mj = fmaxf(mj, acc[i][j][r] * scale);
        }
      mj = fmaxf(mj, __shfl_xor(mj, 16, 64));
      mj = fmaxf(mj, __shfl_xor(mj, 32, 64));
      float zj = 0.f;
#pragma unroll
      for (int i = 0; i < MI; ++i)
#pragma unroll
        for (int r = 0; r < 4; ++r) {
          const int row = r0 + i * 16 + r;
          if (row < L) zj += __expf(acc[i][j][r] * scale - mj);
        }
      zj += __shfl_xor(zj, 16, 64);
      zj += __shfl_xor(zj, 32, 64);
      Ms[j] = mj; Zs[j] = zj;
    }
    if (lane < 16) {
#pragma unroll
      for (int j = 0; j < 4; ++j) red[wm][wn][j][frow] = make_float2(Ms[j], Zs[j]);
    }
    __syncthreads();
    if (wm == 0 && lane < 16) {
#pragma unroll
      for (int j = 0; j < 4; ++j) {
        const float2 a = red[0][wn][j][frow];
        const float2 b = red[1][wn][j][frow];
        const float M = fmaxf(a.x, b.x);
        const float Z = a.y * __expf(a.x - M) + b.y * __expf(b.x - M);
        const int col = tileN + wn * 64 + j * 16 + frow;
        const size_t o = ((size_t)(tileM >> 8) * NB + bz) * T_SEQ + col;
        mpQ[o] = M; zpQ[o] = Z;
      }
    }
  }
}

// ------- combine live chunk partials per column -> m, 1/Z -------------------
__global__ __launch_bounds__(256) void colreduce_comb(const float* __restrict__ mp,
                                                      const float* __restrict__ zp,
                                                      const int* __restrict__ l,
                                                      float* __restrict__ m,
                                                      float* __restrict__ rz) {
  const int b = blockIdx.y;
  const int j = blockIdx.x * 256 + threadIdx.x;
  const int L = l[b];
  float M = -3e38f, Z = 0.f;
  for (int c = 0; c < NCH && (c << 8) < L; ++c) {
    const size_t o = ((size_t)c * NB + b) * T_SEQ + j;
    const float mc = mp[o], zc = zp[o];
    const float nm = fmaxf(M, mc);
    Z = Z * __expf(M - nm) + zc * __expf(mc - nm);
    M = nm;
  }
  m[b * T_SEQ + j] = M;
  rz[b * T_SEQ + j] = 1.f / Z;
}

// ---------------- P = exp(S - m) / Z  (bf16, row-masked) -------------------
// Rows in [L, ceil128(L)) get zeros (read by the PV straddle tile); rows
// beyond ceil128(L) are never read (PV tiles there are skipped) -> no write.
__global__ __launch_bounds__(256) void pbuild(const __half* __restrict__ S,
                                              const int* __restrict__ l,
                                              const float* __restrict__ m,
                                              const float* __restrict__ rz,
                                              u16* __restrict__ P) {
  const int b = blockIdx.x >> 11;
  const int i = blockIdx.x & (T_SEQ - 1);
  const int L = l[b];
  if (i >= ((L + 127) & ~127)) return;
  const int j0 = threadIdx.x * 8;
  const size_t off = ((size_t)blockIdx.x << 11) + j0;
  ushort4 o0, o1;
  if (i < L) {
    const __half* sp = S + off;
    const float* mp = m + b * T_SEQ + j0;
    const float* zp = rz + b * T_SEQ + j0;
    u16 tmp[8];
#pragma unroll
    for (int t = 0; t < 8; ++t)
      tmp[t] = f2bf(__expf(__half2float(sp[t]) - mp[t]) * zp[t]);
    o0 = make_ushort4(tmp[0], tmp[1], tmp[2], tmp[3]);
    o1 = make_ushort4(tmp[4], tmp[5], tmp[6], tmp[7]);
  } else {
    o0 = make_ushort4(0, 0, 0, 0);
    o1 = make_ushort4(0, 0, 0, 0);
  }
  *(ushort4*)(P + off) = o0;
  *(ushort4*)(P + off + 4) = o1;
}

// ---------------------------------------------------------------------------
extern "C" void kernel_launch(void* const* d_in, const int* in_sizes, int n_in,
                              void* d_out, int out_size, void* d_ws, size_t ws_size,
                              hipStream_t stream) {
  (void)in_sizes; (void)n_in; (void)out_size; (void)ws_size;
  const float* x     = (const float*)d_in[0];
  const int*   l     = (const int*)d_in[1];
  const float* Wq    = (const float*)d_in[2];
  const float* Wk    = (const float*)d_in[3];
  const float* Wv    = (const float*)d_in[4];
  const float* Wo    = (const float*)d_in[5];
  const float* bo    = (const float*)d_in[6];
  const float* gamma = (const float*)d_in[7];
  const float* beta  = (const float*)d_in[8];

  char* ws = (char*)d_ws;
  const size_t MiB = 1024 * 1024;
  u16* xn   = (u16*)(ws);             // 16 MiB x_norm; later reused as y
  u16* wqkb = (u16*)(ws + 16 * MiB);  // 4 MiB: Wq rows then Wk rows (concat)
  u16* wvb  = (u16*)(ws + 20 * MiB);  // 2 MiB; later reused for softmax partials
  u16* wob  = (u16*)(ws + 22 * MiB);  // 2 MiB
  u16* QKb  = (u16*)(ws + 24 * MiB);  // 32 MiB: [8192][2048] Q|K; reused as P
  u16* Vt   = (u16*)(ws + 56 * MiB);  // 16 MiB: [1024][8192] V^T (all batches)
  float* mpart = (float*)(ws + 20 * MiB);                // 256 KiB (over dead wvb)
  float* zpart = (float*)(ws + 20 * MiB + 512 * 1024);   // 256 KiB
  float* mb  = (float*)(ws + 72 * MiB);
  float* rzb = (float*)(ws + 72 * MiB + 32 * 1024);
  u16* Pb = QKb;                      // P overwrites dead Q|K
  u16* yb = xn;
  __half* S = (__half*)d_out;         // d_out doubles as the 32 MiB score scratch
  float* outp = (float*)d_out;

  const long TD = (long)T_SEQ * DIM, TT = (long)T_SEQ * T_SEQ;
  const long TQK = (long)T_SEQ * 2048;

  ln_kernel<<<NB * T_SEQ, 256, 0, stream>>>(x, gamma, beta, xn);
  wcvt4<<<4096, 256, 0, stream>>>(Wq, Wk, Wv, Wo, wqkb, wvb, wob);

  // Q|K = xn @ [Wq;Wk]^T   [8192,2048]   grid 8x32 = 256  (dead Q-tiles skip)
  gemm_bt<0, 256, 3><<<dim3(8, 32, 1), 512, 0, stream>>>(
      xn, wqkb, QKb, DIM, DIM, DIM, 2048, 0, 0, 0, nullptr, 0, 0.f,
      l, nullptr, nullptr);
  // V^T = Wv_bf @ xn^T   [1024, 8192]    grid 32x8 = 256
  gemm_bt<0, 128, 0><<<dim3(32, 8, 1), 512, 0, stream>>>(
      wvb, xn, Vt, DIM, DIM, DIM, 8192, 0, 0, 0, nullptr, 0, 0.f,
      nullptr, nullptr, nullptr);
  // S[b] = (Q_b @ K_b^T)*scale -> fp16, + fused per-column partial (m,z)
  // (tiles with all rows masked skip entirely)
  gemm_bt<1, 256, 1><<<dim3(8, 8, NB), 512, 0, stream>>>(
      QKb, QKb + 1024, S, DIM, 2048, 2048, T_SEQ, TQK, TQK, TT, nullptr, 0, 0.03125f,
      l, mpart, zpart);
  // combine live chunk partials -> m, 1/Z
  colreduce_comb<<<dim3(T_SEQ / 256, NB), 256, 0, stream>>>(mpart, zpart, l, mb, rzb);
  // P = exp(S-m)*rz (bf16), zero straddle band, skip fully-dead rows
  pbuild<<<NB * T_SEQ, 256, 0, stream>>>(S, l, mb, rzb, Pb);
  // y[b] = x_b + P_b @ Vt_b^T   [2048,1024] bf16   grid 4x16x4 = 256
  // (tiles with all P-rows zero emit y = x directly)
  gemm_bt<2, 128, 2><<<dim3(4, 16, NB), 512, 0, stream>>>(
      Pb, Vt, yb, T_SEQ, T_SEQ, 8192, DIM, TT, 2048, TD, x, TD, 0.f,
      l, nullptr, nullptr);
  // out = relu(y @ Wo^T + bo)   f32        grid 4x64 = 256
  gemm_bt<3, 128, 0><<<dim3(4, 64, 1), 512, 0, stream>>>(
      yb, wob, outp, DIM, DIM, DIM, DIM, 0, 0, 0, bo, 0, 0.f,
      nullptr, nullptr, nullptr);
}